// Round 15
// baseline (232.287 us; speedup 1.0000x reference)
//
#include <hip/hip_runtime.h>
#include <stdint.h>

typedef __bf16 bf16x8_t __attribute__((ext_vector_type(8)));
typedef float f32x4_t __attribute__((ext_vector_type(4)));

#define AS1 __attribute__((address_space(1)))
#define AS3 __attribute__((address_space(3)))

static __device__ __forceinline__ unsigned short f2bf(float f) {
  union { float f; unsigned u; } a;
  a.f = f;
  unsigned r = a.u + 0x7fffu + ((a.u >> 16) & 1u);
  return (unsigned short)(r >> 16);
}

static __device__ __forceinline__ float bf2f(unsigned short u) {
  union { unsigned u; float f; } a;
  a.u = (unsigned)u << 16;
  return a.f;
}

// HW packed f32x2 -> bf16x2 (RNE)
static __device__ __forceinline__ unsigned cvtpk(float lo, float hi) {
  unsigned r;
  asm("v_cvt_pk_bf16_f32 %0, %1, %2" : "=v"(r) : "v"(lo), "v"(hi));
  return r;
}

// ---------- 0. packed bf16 {cos,sin} table: one uint per (t,d) ----------
__global__ void build_cs(const float* __restrict__ sinp, const float* __restrict__ cosp,
                         unsigned* __restrict__ cs) {
  const int i = blockIdx.x * 256 + threadIdx.x;
  cs[i] = (unsigned)f2bf(cosp[i]) | ((unsigned)f2bf(sinp[i]) << 16);
}

// ---------- 1. fp32 -> bf16 elementwise ----------
__global__ void cvt_bf16_kernel(const float* __restrict__ in, unsigned short* __restrict__ out) {
  long i = ((long)blockIdx.x * blockDim.x + threadIdx.x) * 4;
  float4 v = *(const float4*)(in + i);
  ushort4 o;
  o.x = f2bf(v.x);
  o.y = f2bf(v.y);
  o.z = f2bf(v.z);
  o.w = f2bf(v.w);
  *(ushort4*)(out + i) = o;
}

// ---------- 2. fp32 [R][C] (row stride ld) -> bf16 [C][R] ----------
__global__ void transpose_f32_bf16(const float* __restrict__ src, unsigned short* __restrict__ dst,
                                   int ld, int dld, long sbs, long dbs) {
  __shared__ float tile[64][65];
  src += (long)blockIdx.z * sbs;
  dst += (long)blockIdx.z * dbs;
  const int c0 = blockIdx.x * 64, r0 = blockIdx.y * 64;
  const int tx = threadIdx.x, ty = threadIdx.y;
#pragma unroll
  for (int j = 0; j < 64; j += 4)
    tile[ty + j][tx] = src[(long)(r0 + ty + j) * ld + (c0 + tx)];
  __syncthreads();
#pragma unroll
  for (int j = 0; j < 64; j += 4)
    dst[(long)(c0 + ty + j) * dld + (r0 + tx)] = f2bf(tile[tx][ty + j]);
}

#define STAGE_G(Abase, Bbase, buf, kt)                                                \
  {                                                                                   \
    _Pragma("unroll") for (int i = 0; i < 2; i++) {                                   \
      const int chunk = (i * 4 + wid) * 64 + lane;                                    \
      const int row = chunk >> 2;                                                     \
      __builtin_amdgcn_global_load_lds(                                               \
          (const AS1 void*)(A + (bm + row) * K + (kt) + sslot * 8),                   \
          (AS3 void*)(Abase + buf * 4096 + chunk * 8), 16, 0, 0);                     \
      __builtin_amdgcn_global_load_lds(                                               \
          (const AS1 void*)(Bt + (bn + row) * K + (kt) + sslot * 8),                  \
          (AS3 void*)(Bbase + buf * 4096 + chunk * 8), 16, 0, 0);                     \
    }                                                                                 \
  }

// ---------- 3. GEMM (r9 pipeline: 3-buf LDS, counted vmcnt, slot swizzle) ----------
__global__ __launch_bounds__(256) void gemm_bt(const unsigned short* __restrict__ A,
                                               const unsigned short* __restrict__ Bt,
                                               float* __restrict__ C,
                                               int M, int N, int K, int nx) {
  __shared__ unsigned short As[3][128 * 32];
  __shared__ unsigned short Bs[3][128 * 32];
  const int nwg = gridDim.x;
  const int bid = blockIdx.x;
  const int swz = (bid & 7) * (nwg >> 3) + (bid >> 3);
  const int by = swz / nx;
  const int bx = swz - by * nx;

  const int tid = threadIdx.x;
  const int wid = tid >> 6, lane = tid & 63;
  const int r16 = lane & 15, g = lane >> 4;
  const long bm = (long)by * 128;
  const long bn = (long)bx * 128;
  const int wr = (wid >> 1) * 64, wc = (wid & 1) * 64;
  const int gr = g ^ (r16 & 3);
  const int sslot = (lane & 3) ^ ((lane >> 2) & 3);

  f32x4_t acc[4][4];
#pragma unroll
  for (int i = 0; i < 4; i++)
#pragma unroll
    for (int j = 0; j < 4; j++) acc[i][j] = (f32x4_t){0.f, 0.f, 0.f, 0.f};

  const int NT = K >> 5;
  unsigned short* Ab = &As[0][0];
  unsigned short* Bb = &Bs[0][0];

  STAGE_G(Ab, Bb, 0, 0)
  STAGE_G(Ab, Bb, 1, 32)
  asm volatile("s_waitcnt vmcnt(4)" ::: "memory");
  __builtin_amdgcn_s_barrier();

  for (int T = 0; T < NT; T++) {
    const int cur = T % 3;
    if (T + 2 < NT) {
      const int nb = (T + 2) % 3;
      STAGE_G(Ab, Bb, nb, (T + 2) * 32)
    }
    __builtin_amdgcn_sched_barrier(0);
    bf16x8_t af[4], bfr[4];
#pragma unroll
    for (int mi = 0; mi < 4; mi++)
      af[mi] = *(const bf16x8_t*)(Ab + cur * 4096 + (wr + mi * 16 + r16) * 32 + gr * 8);
#pragma unroll
    for (int ni = 0; ni < 4; ni++)
      bfr[ni] = *(const bf16x8_t*)(Bb + cur * 4096 + (wc + ni * 16 + r16) * 32 + gr * 8);
    __builtin_amdgcn_s_setprio(1);
#pragma unroll
    for (int mi = 0; mi < 4; mi++)
#pragma unroll
      for (int ni = 0; ni < 4; ni++)
        acc[mi][ni] = __builtin_amdgcn_mfma_f32_16x16x32_bf16(af[mi], bfr[ni], acc[mi][ni], 0, 0, 0);
    __builtin_amdgcn_s_setprio(0);
    if (T + 2 < NT)
      asm volatile("s_waitcnt vmcnt(4)" ::: "memory");
    else
      asm volatile("s_waitcnt vmcnt(0)" ::: "memory");
    __builtin_amdgcn_s_barrier();
  }

#pragma unroll
  for (int mi = 0; mi < 4; mi++)
#pragma unroll
    for (int ni = 0; ni < 4; ni++) {
      const long rowb = bm + wr + mi * 16 + 4 * g;
      const long colb = bn + wc + ni * 16 + r16;
#pragma unroll
      for (int j = 0; j < 4; j++)
        C[(rowb + j) * N + colb] = acc[mi][ni][j];
    }
}

// ---------- 3b. GEMM1 fused: x @ Wqkv with RoPE + layout epilogue (v3) ----------
// v2 structure (raw acc -> LDS; per-thread contiguous half-row; batched table
// prefetch before the LDS stores) with the table in PACKED BF16 {cos,sin}
// (4B/elem): a 64-elem half-row = 16 uint4 = 64 VGPRs — the WHOLE row resident
// (v2 bug: float2 table needed 32 float4; csr[16] covered only half -> OOB).
__global__ __launch_bounds__(256) void gemm_qkv_rope(
    const unsigned short* __restrict__ A,   // xb [4096][2048]
    const unsigned short* __restrict__ Bt,  // wqkvT [2304][2048]
    const unsigned* __restrict__ cs,        // [2048][128] packed bf16 {cos,sin}
    unsigned short* __restrict__ qr,
    unsigned short* __restrict__ kr,
    unsigned short* __restrict__ vT) {
  __shared__ unsigned short smem[6][128 * 32];  // 48KB; epilogue reuses as 128x130 tile
  const int K = 2048, nx = 18, nwg = 576;
  const int bid = blockIdx.x;
  const int swz = (bid & 7) * (nwg >> 3) + (bid >> 3);
  const int by = swz / nx;
  const int bx = swz - by * nx;

  const int tid = threadIdx.x;
  const int wid = tid >> 6, lane = tid & 63;
  const int r16 = lane & 15, g = lane >> 4;
  const long bm = (long)by * 128;
  const long bn = (long)bx * 128;
  const int wr = (wid >> 1) * 64;
  const int wcp = (wid & 1) * 32;  // remapped cols: wcp + {0,16,64,80} + r16
  const int gr = g ^ (r16 & 3);
  const int sslot = (lane & 3) ^ ((lane >> 2) & 3);
  const int colmap[4] = {0, 16, 64, 80};

  f32x4_t acc[4][4];
#pragma unroll
  for (int i = 0; i < 4; i++)
#pragma unroll
    for (int j = 0; j < 4; j++) acc[i][j] = (f32x4_t){0.f, 0.f, 0.f, 0.f};

  const int NT = K >> 5;  // 64
  unsigned short* Ab = &smem[0][0];
  unsigned short* Bb = &smem[3][0];

  STAGE_G(Ab, Bb, 0, 0)
  STAGE_G(Ab, Bb, 1, 32)
  asm volatile("s_waitcnt vmcnt(4)" ::: "memory");
  __builtin_amdgcn_s_barrier();

  for (int T = 0; T < NT; T++) {
    const int cur = T % 3;
    if (T + 2 < NT) {
      const int nb = (T + 2) % 3;
      STAGE_G(Ab, Bb, nb, (T + 2) * 32)
    }
    __builtin_amdgcn_sched_barrier(0);
    bf16x8_t af[4], bfr[4];
#pragma unroll
    for (int mi = 0; mi < 4; mi++)
      af[mi] = *(const bf16x8_t*)(Ab + cur * 4096 + (wr + mi * 16 + r16) * 32 + gr * 8);
#pragma unroll
    for (int ni = 0; ni < 4; ni++)
      bfr[ni] = *(const bf16x8_t*)(Bb + cur * 4096 + (wcp + colmap[ni] + r16) * 32 + gr * 8);
    __builtin_amdgcn_s_setprio(1);
#pragma unroll
    for (int mi = 0; mi < 4; mi++)
#pragma unroll
      for (int ni = 0; ni < 4; ni++)
        acc[mi][ni] = __builtin_amdgcn_mfma_f32_16x16x32_bf16(af[mi], bfr[ni], acc[mi][ni], 0, 0, 0);
    __builtin_amdgcn_s_setprio(0);
    if (T + 2 < NT)
      asm volatile("s_waitcnt vmcnt(4)" ::: "memory");
    else
      asm volatile("s_waitcnt vmcnt(0)" ::: "memory");
    __builtin_amdgcn_s_barrier();
  }
  // ---- fused epilogue (K-loop ended on a full barrier: smem free) ----
  const int b = by >> 4;
  const int tseq0 = (by & 15) * 128;
  const int LDT = 130;  // 65 dwords/row == 1 mod 32 -> conflict-free row reads
  unsigned short* sm = &smem[0][0];
  const int row2 = tid >> 1, half = (tid & 1) * 64;

  if (bx < 17) {  // q-head (bx<16) or k (bx==16): RoPE path
    const bool isq = (bx < 16);
    // batched coalesced table prefetch: 16 uint4 = ALL 64 packed {cos,sin}
    uint4 csr[16];
    {
      const uint4* csp = (const uint4*)(cs + (long)(tseq0 + row2) * 128 + half);
#pragma unroll
      for (int i = 0; i < 16; i++) csr[i] = csp[i];
    }
    __builtin_amdgcn_sched_barrier(0);
    // phase 1: raw acc -> LDS bf16 [t][d]
#pragma unroll
    for (int mi = 0; mi < 4; mi++)
#pragma unroll
      for (int ni = 0; ni < 4; ni++) {
        const int d = wcp + colmap[ni] + r16;
#pragma unroll
        for (int j = 0; j < 4; j++) {
          const int tl = wr + mi * 16 + 4 * g + j;
          sm[tl * LDT + d] = f2bf(acc[mi][ni][j]);
        }
      }
    __syncthreads();
    // phase 2: rope in fp32 on contiguous half-row, coalesced store
    const float qsc = isq ? 0.011271055f : 1.0f;  // 1/128*log2(e) (exp2 softmax)
    const unsigned short* srow = sm + row2 * LDT;
    unsigned short* dst = (isq ? (qr + ((long)(b * 16 + bx) * 2048 + tseq0) * 128)
                               : (kr + ((long)b * 2048 + tseq0) * 128)) +
                          (long)row2 * 128 + half;
    const unsigned* csw = (const unsigned*)&csr[0];  // 64 packed {cos,sin}
#pragma unroll
    for (int i = 0; i < 8; i++) {
      bf16x8_t xv = *(const bf16x8_t*)(srow + half + i * 8);
      bf16x8_t pv = *(const bf16x8_t*)(srow + (half ^ 64) + i * 8);
      const unsigned short* xu = (const unsigned short*)&xv;
      const unsigned short* pu = (const unsigned short*)&pv;
      float v[8];
#pragma unroll
      for (int e = 0; e < 8; e++) {
        const unsigned w = csw[i * 8 + e];
        const float c = bf2f((unsigned short)(w & 0xffffu));
        const float s = bf2f((unsigned short)(w >> 16));
        const float xf = bf2f(xu[e]);
        const float pf = (half == 0) ? -bf2f(pu[e]) : bf2f(pu[e]);
        v[e] = (xf * c + pf * s) * qsc;
      }
      uint4 w4;
      w4.x = cvtpk(v[0], v[1]);
      w4.y = cvtpk(v[2], v[3]);
      w4.z = cvtpk(v[4], v[5]);
      w4.w = cvtpk(v[6], v[7]);
      *(uint4*)(dst + i * 8) = w4;
    }
  } else {  // v: plain cvt, stored transposed [d][t]
#pragma unroll
    for (int mi = 0; mi < 4; mi++)
#pragma unroll
      for (int ni = 0; ni < 4; ni++) {
        const int d = wcp + colmap[ni] + r16;
#pragma unroll
        for (int j = 0; j < 4; j++) {
          const int tl = wr + mi * 16 + 4 * g + j;
          sm[d * LDT + tl] = f2bf(acc[mi][ni][j]);
        }
      }
    __syncthreads();
    unsigned short* dst = vT + (long)b * 128 * 2048 + (long)row2 * 2048 + tseq0 + half;
#pragma unroll
    for (int i = 0; i < 8; i++)
      *(bf16x8_t*)(dst + i * 8) = *(const bf16x8_t*)(sm + row2 * LDT + half + i * 8);
  }
}

// ---------- 5. causal MQA flash attention (v10, unchanged) ----------
__global__ __launch_bounds__(256, 2)
void mqa_attn(const unsigned short* __restrict__ qr,
              const unsigned short* __restrict__ kr,
              const unsigned short* __restrict__ vT,
              unsigned short* __restrict__ ao) {
  __shared__ unsigned short Kb[2][64 * 128];
  __shared__ unsigned short Vb[2][128 * 64];
  __shared__ unsigned short plds[4][16 * 64];
  const int idx = blockIdx.x;
  const int pj = idx & 15, h = (idx >> 4) & 15, b = idx >> 8;
  const int tid = threadIdx.x;
  const int wid = tid >> 6, lane = tid & 63;
  const int r = lane & 15, g = lane >> 4;
  const int rs = r & 7;
  char* pw = (char*)&plds[wid][0];

  const unsigned short* kbase = kr + (long)b * 2048 * 128;
  const unsigned short* vbase = vT + (long)b * 128 * 2048;
  const unsigned short* qh = qr + (long)(b * 16 + h) * 2048 * 128;

  const int scol = (tid & 15) ^ ((tid >> 4) & 7);
  const int vscol = (tid & 7) ^ ((tid >> 3) & 7);

  f32x4_t o[8];
#pragma unroll
  for (int i = 0; i < 8; i++) o[i] = (f32x4_t){0.f, 0.f, 0.f, 0.f};
  float m = 0.f, lsum = 0.f;

  int tile = pj;
  bf16x8_t qf[4];
  {
    const unsigned short* qp = qh + (long)(tile * 64 + wid * 16 + r) * 128 + g * 8;
#pragma unroll
    for (int c = 0; c < 4; c++) qf[c] = *(const bf16x8_t*)(qp + c * 32);
  }

#pragma unroll
  for (int i = 0; i < 4; i++) {
    const int row = i * 16 + (tid >> 4);
    __builtin_amdgcn_global_load_lds(
        (const AS1 void*)(kbase + (long)row * 128 + scol * 8),
        (AS3 void*)(&Kb[0][(i * 256 + tid) * 8]), 16, 0, 0);
  }
#pragma unroll
  for (int i = 0; i < 4; i++) {
    const int vrow = i * 32 + (tid >> 3);
    __builtin_amdgcn_global_load_lds(
        (const AS1 void*)(vbase + (long)vrow * 2048 + vscol * 8),
        (AS3 void*)(&Vb[0][(i * 256 + tid) * 8]), 16, 0, 0);
  }
  asm volatile("s_waitcnt vmcnt(0)" ::: "memory");
  __builtin_amdgcn_s_barrier();

  const int switch_s = pj + 1;
  for (int s = 0; s <= 32; s++) {
    const int cur = s & 1;

    if (s == switch_s) {
      float lt = lsum;
      lt += __shfl_xor(lt, 16);
      lt += __shfl_xor(lt, 32);
      float rl[4];
#pragma unroll
      for (int jj = 0; jj < 4; jj++) rl[jj] = 1.0f / __shfl(lt, 4 * g + jj);
      unsigned short* aop = ao + ((long)(b * 2048 + tile * 64 + wid * 16 + 4 * g)) * 2048 + h * 128 + r;
#pragma unroll
      for (int dt = 0; dt < 8; dt++)
#pragma unroll
        for (int jj = 0; jj < 4; jj++)
          aop[(long)jj * 2048 + dt * 16] = f2bf(o[dt][jj] * rl[jj]);
      tile = 31 - pj;
      const unsigned short* qp = qh + (long)(tile * 64 + wid * 16 + r) * 128 + g * 8;
#pragma unroll
      for (int c = 0; c < 4; c++) qf[c] = *(const bf16x8_t*)(qp + c * 32);
#pragma unroll
      for (int i = 0; i < 8; i++) o[i] = (f32x4_t){0.f, 0.f, 0.f, 0.f};
      m = 0.f;
      lsum = 0.f;
    }

    if (s < 32) {
      const int kvn = (s + 1 <= pj) ? 64 * (s + 1) : 64 * (s - pj);
#pragma unroll
      for (int i = 0; i < 4; i++) {
        const int row = i * 16 + (tid >> 4);
        __builtin_amdgcn_global_load_lds(
            (const AS1 void*)(kbase + (long)(kvn + row) * 128 + scol * 8),
            (AS3 void*)(&Kb[cur ^ 1][(i * 256 + tid) * 8]), 16, 0, 0);
      }
      __builtin_amdgcn_sched_barrier(0);
#pragma unroll
      for (int i = 0; i < 4; i++) {
        const int vrow = i * 32 + (tid >> 3);
        __builtin_amdgcn_global_load_lds(
            (const AS1 void*)(vbase + (long)vrow * 2048 + kvn + vscol * 8),
            (AS3 void*)(&Vb[cur ^ 1][(i * 256 + tid) * 8]), 16, 0, 0);
      }
    }
    __builtin_amdgcn_sched_barrier(0);

    f32x4_t sc[4];
#pragma unroll
    for (int t = 0; t < 4; t++) sc[t] = (f32x4_t){0.f, 0.f, 0.f, 0.f};
    const unsigned short* Kcur = &Kb[cur][0];
    __builtin_amdgcn_s_setprio(1);
#pragma unroll
    for (int t = 0; t < 4; t++) {
      const unsigned short* krow = Kcur + (16 * t + r) * 128;
#pragma unroll
      for (int c = 0; c < 4; c++) {
        const bf16x8_t kf = *(const bf16x8_t*)(krow + (((4 * c + g) ^ rs) << 3));
        sc[t] = __builtin_amdgcn_mfma_f32_16x16x32_bf16(kf, qf[c], sc[t], 0, 0, 0);
      }
    }
    __builtin_amdgcn_s_setprio(0);

    if (s == pj || s == 32) {
#pragma unroll
      for (int t = 0; t < 4; t++)
#pragma unroll
        for (int jj = 0; jj < 4; jj++)
          if (t * 16 + 4 * g + jj > wid * 16 + r) sc[t][jj] = -1e30f;
    }
    float mx01 = fmaxf(fmaxf(sc[0][0], sc[0][1]), fmaxf(sc[0][2], sc[0][3]));
    float mx23 = fmaxf(fmaxf(sc[1][0], sc[1][1]), fmaxf(sc[1][2], sc[1][3]));
    float mx45 = fmaxf(fmaxf(sc[2][0], sc[2][1]), fmaxf(sc[2][2], sc[2][3]));
    float mx67 = fmaxf(fmaxf(sc[3][0], sc[3][1]), fmaxf(sc[3][2], sc[3][3]));
    const float lm = fmaxf(fmaxf(mx01, mx23), fmaxf(mx45, mx67));
    if (!__all(lm <= m + 11.5f)) {
      float pm = lm;
      pm = fmaxf(pm, __shfl_xor(pm, 16));
      pm = fmaxf(pm, __shfl_xor(pm, 32));
      const float mnew = fmaxf(m, pm);
      const float alpha = __builtin_amdgcn_exp2f(m - mnew);
      lsum *= alpha;
      float aj[4];
#pragma unroll
      for (int jj = 0; jj < 4; jj++) aj[jj] = __shfl(alpha, 4 * g + jj);
#pragma unroll
      for (int dt = 0; dt < 8; dt++) {
        o[dt][0] *= aj[0]; o[dt][1] *= aj[1]; o[dt][2] *= aj[2]; o[dt][3] *= aj[3];
      }
      m = mnew;
    }
    float p[16];
#pragma unroll
    for (int t = 0; t < 4; t++)
#pragma unroll
      for (int jj = 0; jj < 4; jj++) p[4 * t + jj] = __builtin_amdgcn_exp2f(sc[t][jj] - m);
    float ls = 0.f;
#pragma unroll
    for (int i = 0; i < 16; i++) ls += p[i];
    lsum += ls;

    asm volatile("" ::: "memory");
#pragma unroll
    for (int t = 0; t < 4; t++) {
      uint2 w = {cvtpk(p[4 * t], p[4 * t + 1]), cvtpk(p[4 * t + 2], p[4 * t + 3])};
      *(uint2*)(pw + r * 128 + (((2 * t + (g >> 1)) ^ rs) << 4) + ((g & 1) << 3)) = w;
    }
    asm volatile("s_waitcnt lgkmcnt(0)" ::: "memory");
    const bf16x8_t pa0 = *(const bf16x8_t*)(pw + r * 128 + ((g ^ rs) << 4));
    const bf16x8_t pa1 = *(const bf16x8_t*)(pw + r * 128 + (((4 + g) ^ rs) << 4));

    if (s < 32)
      asm volatile("s_waitcnt vmcnt(8)" ::: "memory");
    else
      asm volatile("s_waitcnt vmcnt(0)" ::: "memory");
    __builtin_amdgcn_s_barrier();

    const unsigned short* Vcur = &Vb[cur][0];
    __builtin_amdgcn_s_setprio(1);
#pragma unroll
    for (int dt = 0; dt < 8; dt++) {
      const bf16x8_t vfA = *(const bf16x8_t*)(Vcur + (dt * 16 + r) * 64 + ((g ^ rs) << 3));
      o[dt] = __builtin_amdgcn_mfma_f32_16x16x32_bf16(pa0, vfA, o[dt], 0, 0, 0);
    }
#pragma unroll
    for (int dt = 0; dt < 8; dt++) {
      const bf16x8_t vfB = *(const bf16x8_t*)(Vcur + (dt * 16 + r) * 64 + (((4 + g) ^ rs) << 3));
      o[dt] = __builtin_amdgcn_mfma_f32_16x16x32_bf16(pa1, vfB, o[dt], 0, 0, 0);
    }
    __builtin_amdgcn_s_setprio(0);

    if (s < 32)
      asm volatile("s_waitcnt vmcnt(4)" ::: "memory");
    else
      asm volatile("s_waitcnt vmcnt(0)" ::: "memory");
    __builtin_amdgcn_s_barrier();
  }
  {
    float lt = lsum;
    lt += __shfl_xor(lt, 16);
    lt += __shfl_xor(lt, 32);
    float rl[4];
#pragma unroll
    for (int jj = 0; jj < 4; jj++) rl[jj] = 1.0f / __shfl(lt, 4 * g + jj);
    unsigned short* aop = ao + ((long)(b * 2048 + tile * 64 + wid * 16 + 4 * g)) * 2048 + h * 128 + r;
#pragma unroll
    for (int dt = 0; dt < 8; dt++)
#pragma unroll
      for (int jj = 0; jj < 4; jj++)
        aop[(long)jj * 2048 + dt * 16] = f2bf(o[dt][jj] * rl[jj]);
  }
}

extern "C" void kernel_launch(void* const* d_in, const int* in_sizes, int n_in,
                              void* d_out, int out_size, void* d_ws, size_t ws_size,
                              hipStream_t stream) {
  const float* x    = (const float*)d_in[0];
  const float* sinp = (const float*)d_in[1];
  const float* cosp = (const float*)d_in[2];
  const float* Wqkv = (const float*)d_in[3];
  const float* Wo   = (const float*)d_in[4];
  float* out = (float*)d_out;
  char* ws = (char*)d_ws;

  const int B = 2, T = 2048, D = 2048, H = 16, HD = 128;
  const int M = B * T;        // 4096
  const int NQ = D + 2 * HD;  // 2304

  unsigned short* xb    = (unsigned short*)(ws + 0);         // 16,777,216
  unsigned short* wqkvT = (unsigned short*)(ws + 16777216);  //  9,437,184
  unsigned short* woT   = (unsigned short*)(ws + 26214400);  //  8,388,608
  unsigned*       cstab = (unsigned*)      (ws + 34603008);  //  1,048,576
  unsigned short* qr    = (unsigned short*)(ws + 36700160);  // 16,777,216
  unsigned short* kr    = (unsigned short*)(ws + 53477376);  //  1,048,576
  unsigned short* vT    = (unsigned short*)(ws + 54525952);  //  1,048,576
  unsigned short* ao    = xb;  // reuse xb after GEMM1

  dim3 tb(64, 4);
  build_cs<<<(T * HD) / 256, 256, 0, stream>>>(sinp, cosp, cstab);
  cvt_bf16_kernel<<<(M * D) / 1024, 256, 0, stream>>>(x, xb);
  transpose_f32_bf16<<<dim3(NQ / 64, D / 64, 1), tb, 0, stream>>>(Wqkv, wqkvT, NQ, D, 0, 0);
  transpose_f32_bf16<<<dim3(D / 64, D / 64, 1), tb, 0, stream>>>(Wo, woT, D, D, 0, 0);
  gemm_qkv_rope<<<dim3((NQ / 128) * (M / 128)), 256, 0, stream>>>(xb, wqkvT, cstab, qr, kr, vT);
  mqa_attn<<<dim3(512), 256, 0, stream>>>(qr, kr, vT, ao);
  gemm_bt<<<dim3((D / 128) * (M / 128)), 256, 0, stream>>>(ao, woT, out, M, D, D, D / 128);
}

// Round 16
// 202.807 us; speedup vs baseline: 1.1454x; 1.1454x over previous
//
#include <hip/hip_runtime.h>
#include <stdint.h>

typedef __bf16 bf16x8_t __attribute__((ext_vector_type(8)));
typedef float f32x4_t __attribute__((ext_vector_type(4)));

#define AS1 __attribute__((address_space(1)))
#define AS3 __attribute__((address_space(3)))

static __device__ __forceinline__ unsigned short f2bf(float f) {
  union { float f; unsigned u; } a;
  a.f = f;
  unsigned r = a.u + 0x7fffu + ((a.u >> 16) & 1u);
  return (unsigned short)(r >> 16);
}

// HW packed f32x2 -> bf16x2 (RNE) — T12 recipe
static __device__ __forceinline__ unsigned cvtpk(float lo, float hi) {
  unsigned r;
  asm("v_cvt_pk_bf16_f32 %0, %1, %2" : "=v"(r) : "v"(lo), "v"(hi));
  return r;
}

// ---------- 1. fp32 -> bf16 elementwise ----------
__global__ void cvt_bf16_kernel(const float* __restrict__ in, unsigned short* __restrict__ out) {
  long i = ((long)blockIdx.x * blockDim.x + threadIdx.x) * 4;
  float4 v = *(const float4*)(in + i);
  ushort4 o;
  o.x = f2bf(v.x);
  o.y = f2bf(v.y);
  o.z = f2bf(v.z);
  o.w = f2bf(v.w);
  *(ushort4*)(out + i) = o;
}

// ---------- 2. fp32 [R][C] (row stride ld) -> bf16 [C][R] (row stride dld) ----------
__global__ void transpose_f32_bf16(const float* __restrict__ src, unsigned short* __restrict__ dst,
                                   int ld, int dld, long sbs, long dbs) {
  __shared__ float tile[64][65];
  src += (long)blockIdx.z * sbs;
  dst += (long)blockIdx.z * dbs;
  const int c0 = blockIdx.x * 64, r0 = blockIdx.y * 64;
  const int tx = threadIdx.x, ty = threadIdx.y;
#pragma unroll
  for (int j = 0; j < 64; j += 4)
    tile[ty + j][tx] = src[(long)(r0 + ty + j) * ld + (c0 + tx)];
  __syncthreads();
#pragma unroll
  for (int j = 0; j < 64; j += 4)
    dst[(long)(c0 + ty + j) * dld + (r0 + tx)] = f2bf(tile[tx][ty + j]);
}

// ---------- 3. GEMM (round-9 pipeline: 3-buf LDS, counted vmcnt, slot swizzle) ----------
__global__ __launch_bounds__(256) void gemm_bt(const unsigned short* __restrict__ A,
                                               const unsigned short* __restrict__ Bt,
                                               float* __restrict__ C,
                                               int M, int N, int K, int nx) {
  __shared__ unsigned short As[3][128 * 32];
  __shared__ unsigned short Bs[3][128 * 32];
  const int nwg = gridDim.x;
  const int bid = blockIdx.x;
  const int swz = (bid & 7) * (nwg >> 3) + (bid >> 3);  // XCD chunking
  const int by = swz / nx;
  const int bx = swz - by * nx;

  const int tid = threadIdx.x;
  const int wid = tid >> 6, lane = tid & 63;
  const int r16 = lane & 15, g = lane >> 4;
  const long bm = (long)by * 128;
  const long bn = (long)bx * 128;
  const int wr = (wid >> 1) * 64, wc = (wid & 1) * 64;
  const int gr = g ^ (r16 & 3);
  const int sslot = (lane & 3) ^ ((lane >> 2) & 3);

  f32x4_t acc[4][4];
#pragma unroll
  for (int i = 0; i < 4; i++)
#pragma unroll
    for (int j = 0; j < 4; j++) acc[i][j] = (f32x4_t){0.f, 0.f, 0.f, 0.f};

  const int NT = K >> 5;

#define STAGE_G(buf, kt)                                                              \
  {                                                                                   \
    _Pragma("unroll") for (int i = 0; i < 2; i++) {                                   \
      const int chunk = (i * 4 + wid) * 64 + lane;                                    \
      const int row = chunk >> 2;                                                     \
      __builtin_amdgcn_global_load_lds(                                               \
          (const AS1 void*)(A + (bm + row) * K + (kt) + sslot * 8),                   \
          (AS3 void*)(&As[buf][chunk * 8]), 16, 0, 0);                                \
      __builtin_amdgcn_global_load_lds(                                               \
          (const AS1 void*)(Bt + (bn + row) * K + (kt) + sslot * 8),                  \
          (AS3 void*)(&Bs[buf][chunk * 8]), 16, 0, 0);                                \
    }                                                                                 \
  }

  STAGE_G(0, 0)
  STAGE_G(1, 32)
  asm volatile("s_waitcnt vmcnt(4)" ::: "memory");
  __builtin_amdgcn_s_barrier();

  for (int T = 0; T < NT; T++) {
    const int cur = T % 3;
    if (T + 2 < NT) {
      const int nb = (T + 2) % 3;
      STAGE_G(nb, (T + 2) * 32)
    }
    __builtin_amdgcn_sched_barrier(0);
    bf16x8_t af[4], bfr[4];
#pragma unroll
    for (int mi = 0; mi < 4; mi++)
      af[mi] = *(const bf16x8_t*)(&As[cur][(wr + mi * 16 + r16) * 32 + gr * 8]);
#pragma unroll
    for (int ni = 0; ni < 4; ni++)
      bfr[ni] = *(const bf16x8_t*)(&Bs[cur][(wc + ni * 16 + r16) * 32 + gr * 8]);
    __builtin_amdgcn_s_setprio(1);
#pragma unroll
    for (int mi = 0; mi < 4; mi++)
#pragma unroll
      for (int ni = 0; ni < 4; ni++)
        acc[mi][ni] = __builtin_amdgcn_mfma_f32_16x16x32_bf16(af[mi], bfr[ni], acc[mi][ni], 0, 0, 0);
    __builtin_amdgcn_s_setprio(0);
    if (T + 2 < NT)
      asm volatile("s_waitcnt vmcnt(4)" ::: "memory");
    else
      asm volatile("s_waitcnt vmcnt(0)" ::: "memory");
    __builtin_amdgcn_s_barrier();
  }
#undef STAGE_G

#pragma unroll
  for (int mi = 0; mi < 4; mi++)
#pragma unroll
    for (int ni = 0; ni < 4; ni++) {
      const long rowb = bm + wr + mi * 16 + 4 * g;
      const long colb = bn + wc + ni * 16 + r16;
#pragma unroll
      for (int j = 0; j < 4; j++)
        C[(rowb + j) * N + colb] = acc[mi][ni][j];
    }
}

// ---------- 4. RoPE + scale fold + layout ----------
// q scale = 1/128 * log2(e): attention softmax runs in exp2 domain.
__global__ void rope_kernel(const float* __restrict__ qkv,
                            const float* __restrict__ sinp,
                            const float* __restrict__ cosp,
                            unsigned short* __restrict__ qr,
                            unsigned short* __restrict__ kr) {
  const int row = blockIdx.x;  // b*2048 + t
  const int b = row >> 11, t = row & 2047;
  const float* src = qkv + (long)row * 2304;
  const int tid = threadIdx.x;
  const int d = tid & 127;
  const int dp = (d + 64) & 127;
  const float c = cosp[t * 128 + d];
  const float s = sinp[t * 128 + d];
  const float sgn = (d < 64) ? -1.f : 1.f;
  for (int h = (tid >> 7); h < 16; h += 2) {
    const float x0 = src[h * 128 + d];
    const float xp = src[h * 128 + dp];
    qr[((long)((b * 16 + h) * 2048 + t)) * 128 + d] =
        f2bf((x0 * c + sgn * xp * s) * 0.011271055f);
  }
  if (tid < 128) {
    const float x0 = src[2048 + d];
    const float xp = src[2048 + dp];
    kr[((long)(b * 2048 + t)) * 128 + d] = f2bf(x0 * c + sgn * xp * s);
  }
}

// ---------- 5. causal MQA flash attention (v10 = v7 + V-dbuf + exp2 + cvt_pk) ----------
// 512 blocks (tile pj then 31-pj, uniform 33 stages), 16 q-rows/wave.
// K AND V double-buffered in LDS (72KB, 2 blocks/CU). Per stage: issue
// K(s+1) then V(s+1) -> QK -> softmax(exp2) -> P-LDS -> vmcnt(8)+barrier
// (V(s) had a FULL stage to land; K/V(s+1) stay in flight) -> PV ->
// vmcnt(4)+barrier (K(s+1) landed, V(s+1) still flying).
__global__ __launch_bounds__(256, 2)
void mqa_attn(const unsigned short* __restrict__ qr,
              const unsigned short* __restrict__ kr,
              const unsigned short* __restrict__ vT,
              unsigned short* __restrict__ ao) {
  __shared__ unsigned short Kb[2][64 * 128];   // 2 x 16KB K tiles
  __shared__ unsigned short Vb[2][128 * 64];   // 2 x 16KB V^T tiles
  __shared__ unsigned short plds[4][16 * 64];  // per-wave P tile (2KB each)
  const int idx = blockIdx.x;  // 512 blocks
  const int pj = idx & 15, h = (idx >> 4) & 15, b = idx >> 8;
  const int tid = threadIdx.x;
  const int wid = tid >> 6, lane = tid & 63;
  const int r = lane & 15, g = lane >> 4;
  const int rs = r & 7;
  char* pw = (char*)&plds[wid][0];

  const unsigned short* kbase = kr + (long)b * 2048 * 128;
  const unsigned short* vbase = vT + (long)b * 128 * 2048;
  const unsigned short* qh = qr + (long)(b * 16 + h) * 2048 * 128;

  const int scol = (tid & 15) ^ ((tid >> 4) & 7);  // K staging src granule
  const int vscol = (tid & 7) ^ ((tid >> 3) & 7);  // V staging src granule

  f32x4_t o[8];
#pragma unroll
  for (int i = 0; i < 8; i++) o[i] = (f32x4_t){0.f, 0.f, 0.f, 0.f};
  float m = 0.f, lsum = 0.f;

  int tile = pj;
  bf16x8_t qf[4];
  {
    const unsigned short* qp = qh + (long)(tile * 64 + wid * 16 + r) * 128 + g * 8;
#pragma unroll
    for (int c = 0; c < 4; c++) qf[c] = *(const bf16x8_t*)(qp + c * 32);
  }

  // prologue: stage K(0) -> Kb[0], V(0) -> Vb[0]
#pragma unroll
  for (int i = 0; i < 4; i++) {
    const int row = i * 16 + (tid >> 4);
    __builtin_amdgcn_global_load_lds(
        (const AS1 void*)(kbase + (long)row * 128 + scol * 8),
        (AS3 void*)(&Kb[0][(i * 256 + tid) * 8]), 16, 0, 0);
  }
#pragma unroll
  for (int i = 0; i < 4; i++) {
    const int vrow = i * 32 + (tid >> 3);
    __builtin_amdgcn_global_load_lds(
        (const AS1 void*)(vbase + (long)vrow * 2048 + vscol * 8),
        (AS3 void*)(&Vb[0][(i * 256 + tid) * 8]), 16, 0, 0);
  }
  asm volatile("s_waitcnt vmcnt(0)" ::: "memory");
  __builtin_amdgcn_s_barrier();

  const int switch_s = pj + 1;
  for (int s = 0; s <= 32; s++) {
    const int cur = s & 1;

    // 0. tile switch: flush tile A (O stores + Q reload) at stage top
    if (s == switch_s) {
      float lt = lsum;
      lt += __shfl_xor(lt, 16);
      lt += __shfl_xor(lt, 32);
      float rl[4];
#pragma unroll
      for (int jj = 0; jj < 4; jj++) rl[jj] = 1.0f / __shfl(lt, 4 * g + jj);
      unsigned short* aop = ao + ((long)(b * 2048 + tile * 64 + wid * 16 + 4 * g)) * 2048 + h * 128 + r;
#pragma unroll
      for (int dt = 0; dt < 8; dt++)
#pragma unroll
        for (int jj = 0; jj < 4; jj++)
          aop[(long)jj * 2048 + dt * 16] = f2bf(o[dt][jj] * rl[jj]);
      tile = 31 - pj;
      const unsigned short* qp = qh + (long)(tile * 64 + wid * 16 + r) * 128 + g * 8;
#pragma unroll
      for (int c = 0; c < 4; c++) qf[c] = *(const bf16x8_t*)(qp + c * 32);
#pragma unroll
      for (int i = 0; i < 8; i++) o[i] = (f32x4_t){0.f, 0.f, 0.f, 0.f};
      m = 0.f;
      lsum = 0.f;
    }

    // 1. staging for NEXT stage: K(s+1) first, then V(s+1)
    if (s < 32) {
      const int kvn = (s + 1 <= pj) ? 64 * (s + 1) : 64 * (s - pj);
#pragma unroll
      for (int i = 0; i < 4; i++) {
        const int row = i * 16 + (tid >> 4);
        __builtin_amdgcn_global_load_lds(
            (const AS1 void*)(kbase + (long)(kvn + row) * 128 + scol * 8),
            (AS3 void*)(&Kb[cur ^ 1][(i * 256 + tid) * 8]), 16, 0, 0);
      }
      __builtin_amdgcn_sched_barrier(0);
#pragma unroll
      for (int i = 0; i < 4; i++) {
        const int vrow = i * 32 + (tid >> 3);
        __builtin_amdgcn_global_load_lds(
            (const AS1 void*)(vbase + (long)vrow * 2048 + kvn + vscol * 8),
            (AS3 void*)(&Vb[cur ^ 1][(i * 256 + tid) * 8]), 16, 0, 0);
      }
    }
    __builtin_amdgcn_sched_barrier(0);

    // 2. QK^T from LDS K tile
    f32x4_t sc[4];
#pragma unroll
    for (int t = 0; t < 4; t++) sc[t] = (f32x4_t){0.f, 0.f, 0.f, 0.f};
    const unsigned short* Kcur = &Kb[cur][0];
    __builtin_amdgcn_s_setprio(1);
#pragma unroll
    for (int t = 0; t < 4; t++) {
      const unsigned short* krow = Kcur + (16 * t + r) * 128;
#pragma unroll
      for (int c = 0; c < 4; c++) {
        const bf16x8_t kf = *(const bf16x8_t*)(krow + (((4 * c + g) ^ rs) << 3));
        sc[t] = __builtin_amdgcn_mfma_f32_16x16x32_bf16(kf, qf[c], sc[t], 0, 0, 0);
      }
    }
    __builtin_amdgcn_s_setprio(0);

    // 3. causal mask on the current tile's last stage
    if (s == pj || s == 32) {
#pragma unroll
      for (int t = 0; t < 4; t++)
#pragma unroll
        for (int jj = 0; jj < 4; jj++)
          if (t * 16 + 4 * g + jj > wid * 16 + r) sc[t][jj] = -1e30f;
    }
    // 4. softmax in exp2 domain (defer-max fast path), fmax TREE
    float mx01 = fmaxf(fmaxf(sc[0][0], sc[0][1]), fmaxf(sc[0][2], sc[0][3]));
    float mx23 = fmaxf(fmaxf(sc[1][0], sc[1][1]), fmaxf(sc[1][2], sc[1][3]));
    float mx45 = fmaxf(fmaxf(sc[2][0], sc[2][1]), fmaxf(sc[2][2], sc[2][3]));
    float mx67 = fmaxf(fmaxf(sc[3][0], sc[3][1]), fmaxf(sc[3][2], sc[3][3]));
    const float lm = fmaxf(fmaxf(mx01, mx23), fmaxf(mx45, mx67));
    if (!__all(lm <= m + 11.5f)) {  // rare rescale path (11.5 bits ~ 8 nats)
      float pm = lm;
      pm = fmaxf(pm, __shfl_xor(pm, 16));
      pm = fmaxf(pm, __shfl_xor(pm, 32));
      const float mnew = fmaxf(m, pm);
      const float alpha = __builtin_amdgcn_exp2f(m - mnew);
      lsum *= alpha;
      float aj[4];
#pragma unroll
      for (int jj = 0; jj < 4; jj++) aj[jj] = __shfl(alpha, 4 * g + jj);
#pragma unroll
      for (int dt = 0; dt < 8; dt++) {
        o[dt][0] *= aj[0]; o[dt][1] *= aj[1]; o[dt][2] *= aj[2]; o[dt][3] *= aj[3];
      }
      m = mnew;
    }
    float p[16];
#pragma unroll
    for (int t = 0; t < 4; t++)
#pragma unroll
      for (int jj = 0; jj < 4; jj++) p[4 * t + jj] = __builtin_amdgcn_exp2f(sc[t][jj] - m);
    float ls = 0.f;
#pragma unroll
    for (int i = 0; i < 16; i++) ls += p[i];
    lsum += ls;

    // 5. P redistribute through per-wave LDS tile (HW cvt_pk packing)
    asm volatile("" ::: "memory");
#pragma unroll
    for (int t = 0; t < 4; t++) {
      uint2 w = {cvtpk(p[4 * t], p[4 * t + 1]), cvtpk(p[4 * t + 2], p[4 * t + 3])};
      *(uint2*)(pw + r * 128 + (((2 * t + (g >> 1)) ^ rs) << 4) + ((g & 1) << 3)) = w;
    }
    asm volatile("s_waitcnt lgkmcnt(0)" ::: "memory");
    const bf16x8_t pa0 = *(const bf16x8_t*)(pw + r * 128 + ((g ^ rs) << 4));
    const bf16x8_t pa1 = *(const bf16x8_t*)(pw + r * 128 + (((4 + g) ^ rs) << 4));

    // 6. V(s) visibility: staged a FULL stage ago; only K/V(s+1) are newer
    if (s < 32)
      asm volatile("s_waitcnt vmcnt(8)" ::: "memory");
    else
      asm volatile("s_waitcnt vmcnt(0)" ::: "memory");
    __builtin_amdgcn_s_barrier();

    // 7. PV from LDS V tile
    const unsigned short* Vcur = &Vb[cur][0];
    __builtin_amdgcn_s_setprio(1);
#pragma unroll
    for (int dt = 0; dt < 8; dt++) {
      const bf16x8_t vfA = *(const bf16x8_t*)(Vcur + (dt * 16 + r) * 64 + ((g ^ rs) << 3));
      o[dt] = __builtin_amdgcn_mfma_f32_16x16x32_bf16(pa0, vfA, o[dt], 0, 0, 0);
    }
#pragma unroll
    for (int dt = 0; dt < 8; dt++) {
      const bf16x8_t vfB = *(const bf16x8_t*)(Vcur + (dt * 16 + r) * 64 + (((4 + g) ^ rs) << 3));
      o[dt] = __builtin_amdgcn_mfma_f32_16x16x32_bf16(pa1, vfB, o[dt], 0, 0, 0);
    }
    __builtin_amdgcn_s_setprio(0);

    // 8. end: K(s+1) landed (V(s+1) may still fly) -> next stage QK safe
    if (s < 32)
      asm volatile("s_waitcnt vmcnt(4)" ::: "memory");
    else
      asm volatile("s_waitcnt vmcnt(0)" ::: "memory");
    __builtin_amdgcn_s_barrier();
  }
  // epilogue: flush tile B
  {
    float lt = lsum;
    lt += __shfl_xor(lt, 16);
    lt += __shfl_xor(lt, 32);
    float rl[4];
#pragma unroll
    for (int jj = 0; jj < 4; jj++) rl[jj] = 1.0f / __shfl(lt, 4 * g + jj);
    unsigned short* aop = ao + ((long)(b * 2048 + tile * 64 + wid * 16 + 4 * g)) * 2048 + h * 128 + r;
#pragma unroll
    for (int dt = 0; dt < 8; dt++)
#pragma unroll
      for (int jj = 0; jj < 4; jj++)
        aop[(long)jj * 2048 + dt * 16] = f2bf(o[dt][jj] * rl[jj]);
  }
}

extern "C" void kernel_launch(void* const* d_in, const int* in_sizes, int n_in,
                              void* d_out, int out_size, void* d_ws, size_t ws_size,
                              hipStream_t stream) {
  const float* x    = (const float*)d_in[0];
  const float* sinp = (const float*)d_in[1];
  const float* cosp = (const float*)d_in[2];
  const float* Wqkv = (const float*)d_in[3];
  const float* Wo   = (const float*)d_in[4];
  float* out = (float*)d_out;
  char* ws = (char*)d_ws;

  const int B = 2, T = 2048, D = 2048, H = 16, HD = 128;
  const int M = B * T;        // 4096
  const int NQ = D + 2 * HD;  // 2304

  unsigned short* xb    = (unsigned short*)(ws + 0);         // 16,777,216
  unsigned short* wqkvT = (unsigned short*)(ws + 16777216);  //  9,437,184
  unsigned short* woT   = (unsigned short*)(ws + 26214400);  //  8,388,608
  float*          qkv   = (float*)         (ws + 34603008);  // 37,748,736
  unsigned short* qr    = (unsigned short*)(ws + 72351744);  // 16,777,216
  unsigned short* kr    = (unsigned short*)(ws + 89128960);  //  1,048,576
  unsigned short* vT    = (unsigned short*)(ws + 90177536);  //  1,048,576
  unsigned short* ao    = xb;  // reuse xb after first GEMM

  dim3 tb(64, 4);
  cvt_bf16_kernel<<<(M * D) / 1024, 256, 0, stream>>>(x, xb);
  transpose_f32_bf16<<<dim3(NQ / 64, D / 64, 1), tb, 0, stream>>>(Wqkv, wqkvT, NQ, D, 0, 0);
  transpose_f32_bf16<<<dim3(D / 64, D / 64, 1), tb, 0, stream>>>(Wo, woT, D, D, 0, 0);
  gemm_bt<<<dim3((NQ / 128) * (M / 128)), 256, 0, stream>>>(xb, wqkvT, qkv, M, NQ, D, NQ / 128);
  rope_kernel<<<M, 256, 0, stream>>>(qkv, sinp, cosp, qr, kr);
  transpose_f32_bf16<<<dim3(HD / 64, T / 64, B), tb, 0, stream>>>(
      qkv + 2176, vT, NQ, T, (long)T * NQ, (long)HD * T);
  mqa_attn<<<dim3(512), 256, 0, stream>>>(qr, kr, vT, ao);
  gemm_bt<<<dim3((D / 128) * (M / 128)), 256, 0, stream>>>(ao, woT, out, M, D, D, D / 128);
}

// Round 17
// 197.740 us; speedup vs baseline: 1.1747x; 1.0256x over previous
//
#include <hip/hip_runtime.h>
#include <stdint.h>

typedef __bf16 bf16x8_t __attribute__((ext_vector_type(8)));
typedef float f32x4_t __attribute__((ext_vector_type(4)));

#define AS1 __attribute__((address_space(1)))
#define AS3 __attribute__((address_space(3)))

static __device__ __forceinline__ unsigned short f2bf(float f) {
  union { float f; unsigned u; } a;
  a.f = f;
  unsigned r = a.u + 0x7fffu + ((a.u >> 16) & 1u);
  return (unsigned short)(r >> 16);
}

static __device__ __forceinline__ float bf2f(unsigned short u) {
  union { unsigned u; float f; } a;
  a.u = (unsigned)u << 16;
  return a.f;
}

// HW packed f32x2 -> bf16x2 (RNE)
static __device__ __forceinline__ unsigned cvtpk(float lo, float hi) {
  unsigned r;
  asm("v_cvt_pk_bf16_f32 %0, %1, %2" : "=v"(r) : "v"(lo), "v"(hi));
  return r;
}

// ---------- 1. fp32 -> bf16 elementwise ----------
__global__ void cvt_bf16_kernel(const float* __restrict__ in, unsigned short* __restrict__ out) {
  long i = ((long)blockIdx.x * blockDim.x + threadIdx.x) * 4;
  float4 v = *(const float4*)(in + i);
  ushort4 o;
  o.x = f2bf(v.x);
  o.y = f2bf(v.y);
  o.z = f2bf(v.z);
  o.w = f2bf(v.w);
  *(ushort4*)(out + i) = o;
}

// ---------- 2a. fp32 [R][C] -> bf16 [C][R] (weights) ----------
__global__ void transpose_f32_bf16(const float* __restrict__ src, unsigned short* __restrict__ dst,
                                   int ld, int dld, long sbs, long dbs) {
  __shared__ float tile[64][65];
  src += (long)blockIdx.z * sbs;
  dst += (long)blockIdx.z * dbs;
  const int c0 = blockIdx.x * 64, r0 = blockIdx.y * 64;
  const int tx = threadIdx.x, ty = threadIdx.y;
#pragma unroll
  for (int j = 0; j < 64; j += 4)
    tile[ty + j][tx] = src[(long)(r0 + ty + j) * ld + (c0 + tx)];
  __syncthreads();
#pragma unroll
  for (int j = 0; j < 64; j += 4)
    dst[(long)(c0 + ty + j) * dld + (r0 + tx)] = f2bf(tile[tx][ty + j]);
}

// ---------- 2b. bf16 [R][C] -> bf16 [C][R] (V tile; [64][66] pad = conflict-free) ----------
__global__ void transpose_bf16(const unsigned short* __restrict__ src,
                               unsigned short* __restrict__ dst,
                               int ld, int dld, long sbs, long dbs) {
  __shared__ unsigned short tile[64][66];
  src += (long)blockIdx.z * sbs;
  dst += (long)blockIdx.z * dbs;
  const int c0 = blockIdx.x * 64, r0 = blockIdx.y * 64;
  const int tx = threadIdx.x, ty = threadIdx.y;
#pragma unroll
  for (int j = 0; j < 64; j += 4)
    tile[ty + j][tx] = src[(long)(r0 + ty + j) * ld + (c0 + tx)];
  __syncthreads();
#pragma unroll
  for (int j = 0; j < 64; j += 4)
    dst[(long)(c0 + ty + j) * dld + (r0 + tx)] = tile[tx][ty + j];
}

#define STAGE_G(buf, kt)                                                              \
  {                                                                                   \
    _Pragma("unroll") for (int i = 0; i < 2; i++) {                                   \
      const int chunk = (i * 4 + wid) * 64 + lane;                                    \
      const int row = chunk >> 2;                                                     \
      __builtin_amdgcn_global_load_lds(                                               \
          (const AS1 void*)(A + (bm + row) * K + (kt) + sslot * 8),                   \
          (AS3 void*)(&As[buf][chunk * 8]), 16, 0, 0);                                \
      __builtin_amdgcn_global_load_lds(                                               \
          (const AS1 void*)(Bt + (bn + row) * K + (kt) + sslot * 8),                  \
          (AS3 void*)(&Bs[buf][chunk * 8]), 16, 0, 0);                                \
    }                                                                                 \
  }

// ---------- 3a. GEMM fp32-out (r9 pipeline: 3-buf LDS, counted vmcnt, slot swizzle) ----------
__global__ __launch_bounds__(256) void gemm_bt(const unsigned short* __restrict__ A,
                                               const unsigned short* __restrict__ Bt,
                                               float* __restrict__ C,
                                               int M, int N, int K, int nx) {
  __shared__ unsigned short As[3][128 * 32];
  __shared__ unsigned short Bs[3][128 * 32];
  const int nwg = gridDim.x;
  const int bid = blockIdx.x;
  const int swz = (bid & 7) * (nwg >> 3) + (bid >> 3);
  const int by = swz / nx;
  const int bx = swz - by * nx;

  const int tid = threadIdx.x;
  const int wid = tid >> 6, lane = tid & 63;
  const int r16 = lane & 15, g = lane >> 4;
  const long bm = (long)by * 128;
  const long bn = (long)bx * 128;
  const int wr = (wid >> 1) * 64, wc = (wid & 1) * 64;
  const int gr = g ^ (r16 & 3);
  const int sslot = (lane & 3) ^ ((lane >> 2) & 3);

  f32x4_t acc[4][4];
#pragma unroll
  for (int i = 0; i < 4; i++)
#pragma unroll
    for (int j = 0; j < 4; j++) acc[i][j] = (f32x4_t){0.f, 0.f, 0.f, 0.f};

  const int NT = K >> 5;

  STAGE_G(0, 0)
  STAGE_G(1, 32)
  asm volatile("s_waitcnt vmcnt(4)" ::: "memory");
  __builtin_amdgcn_s_barrier();

  for (int T = 0; T < NT; T++) {
    const int cur = T % 3;
    if (T + 2 < NT) {
      const int nb = (T + 2) % 3;
      STAGE_G(nb, (T + 2) * 32)
    }
    __builtin_amdgcn_sched_barrier(0);
    bf16x8_t af[4], bfr[4];
#pragma unroll
    for (int mi = 0; mi < 4; mi++)
      af[mi] = *(const bf16x8_t*)(&As[cur][(wr + mi * 16 + r16) * 32 + gr * 8]);
#pragma unroll
    for (int ni = 0; ni < 4; ni++)
      bfr[ni] = *(const bf16x8_t*)(&Bs[cur][(wc + ni * 16 + r16) * 32 + gr * 8]);
    __builtin_amdgcn_s_setprio(1);
#pragma unroll
    for (int mi = 0; mi < 4; mi++)
#pragma unroll
      for (int ni = 0; ni < 4; ni++)
        acc[mi][ni] = __builtin_amdgcn_mfma_f32_16x16x32_bf16(af[mi], bfr[ni], acc[mi][ni], 0, 0, 0);
    __builtin_amdgcn_s_setprio(0);
    if (T + 2 < NT)
      asm volatile("s_waitcnt vmcnt(4)" ::: "memory");
    else
      asm volatile("s_waitcnt vmcnt(0)" ::: "memory");
    __builtin_amdgcn_s_barrier();
  }

#pragma unroll
  for (int mi = 0; mi < 4; mi++)
#pragma unroll
    for (int ni = 0; ni < 4; ni++) {
      const long rowb = bm + wr + mi * 16 + 4 * g;
      const long colb = bn + wc + ni * 16 + r16;
#pragma unroll
      for (int j = 0; j < 4; j++)
        C[(rowb + j) * N + colb] = acc[mi][ni][j];
    }
}

// ---------- 3b. GEMM bf16-out (identical pipeline; halves C write traffic) ----------
__global__ __launch_bounds__(256) void gemm_bt_h(const unsigned short* __restrict__ A,
                                                 const unsigned short* __restrict__ Bt,
                                                 unsigned short* __restrict__ C,
                                                 int M, int N, int K, int nx) {
  __shared__ unsigned short As[3][128 * 32];
  __shared__ unsigned short Bs[3][128 * 32];
  const int nwg = gridDim.x;
  const int bid = blockIdx.x;
  const int swz = (bid & 7) * (nwg >> 3) + (bid >> 3);
  const int by = swz / nx;
  const int bx = swz - by * nx;

  const int tid = threadIdx.x;
  const int wid = tid >> 6, lane = tid & 63;
  const int r16 = lane & 15, g = lane >> 4;
  const long bm = (long)by * 128;
  const long bn = (long)bx * 128;
  const int wr = (wid >> 1) * 64, wc = (wid & 1) * 64;
  const int gr = g ^ (r16 & 3);
  const int sslot = (lane & 3) ^ ((lane >> 2) & 3);

  f32x4_t acc[4][4];
#pragma unroll
  for (int i = 0; i < 4; i++)
#pragma unroll
    for (int j = 0; j < 4; j++) acc[i][j] = (f32x4_t){0.f, 0.f, 0.f, 0.f};

  const int NT = K >> 5;

  STAGE_G(0, 0)
  STAGE_G(1, 32)
  asm volatile("s_waitcnt vmcnt(4)" ::: "memory");
  __builtin_amdgcn_s_barrier();

  for (int T = 0; T < NT; T++) {
    const int cur = T % 3;
    if (T + 2 < NT) {
      const int nb = (T + 2) % 3;
      STAGE_G(nb, (T + 2) * 32)
    }
    __builtin_amdgcn_sched_barrier(0);
    bf16x8_t af[4], bfr[4];
#pragma unroll
    for (int mi = 0; mi < 4; mi++)
      af[mi] = *(const bf16x8_t*)(&As[cur][(wr + mi * 16 + r16) * 32 + gr * 8]);
#pragma unroll
    for (int ni = 0; ni < 4; ni++)
      bfr[ni] = *(const bf16x8_t*)(&Bs[cur][(wc + ni * 16 + r16) * 32 + gr * 8]);
    __builtin_amdgcn_s_setprio(1);
#pragma unroll
    for (int mi = 0; mi < 4; mi++)
#pragma unroll
      for (int ni = 0; ni < 4; ni++)
        acc[mi][ni] = __builtin_amdgcn_mfma_f32_16x16x32_bf16(af[mi], bfr[ni], acc[mi][ni], 0, 0, 0);
    __builtin_amdgcn_s_setprio(0);
    if (T + 2 < NT)
      asm volatile("s_waitcnt vmcnt(4)" ::: "memory");
    else
      asm volatile("s_waitcnt vmcnt(0)" ::: "memory");
    __builtin_amdgcn_s_barrier();
  }

#pragma unroll
  for (int mi = 0; mi < 4; mi++)
#pragma unroll
    for (int ni = 0; ni < 4; ni++) {
      const long rowb = bm + wr + mi * 16 + 4 * g;
      const long colb = bn + wc + ni * 16 + r16;
#pragma unroll
      for (int j = 0; j < 4; j++)
        C[(rowb + j) * N + colb] = f2bf(acc[mi][ni][j]);
    }
}
#undef STAGE_G

// ---------- 4. RoPE (bf16 in, vectorized) + scale fold + layout ----------
// qkvh bf16 [4096][2304] -> qr (b,h,t,128) scaled 1/128*log2(e), kr (b,t,128).
// Thread handles 8 contiguous d (bf16x8) + partner half (d^64), fp32 cos/sin
// as float4 pairs, cvt_pk packed uint4 stores. All loads/stores coalesced.
__global__ void rope_h(const unsigned short* __restrict__ qkvh,
                       const float* __restrict__ sinp,
                       const float* __restrict__ cosp,
                       unsigned short* __restrict__ qr,
                       unsigned short* __restrict__ kr) {
  const int row = blockIdx.x;  // b*2048 + t
  const int b = row >> 11, t = row & 2047;
  const unsigned short* src = qkvh + (long)row * 2304;
  const int tid = threadIdx.x;
  const int l16 = tid & 15;
  const int d0 = l16 * 8;
  const float sgn = (d0 < 64) ? -1.f : 1.f;

  // cos/sin for d0..d0+7 (fp32, contiguous)
  float c[8], s[8];
  {
    const float4* cp = (const float4*)(cosp + t * 128 + d0);
    const float4* sp = (const float4*)(sinp + t * 128 + d0);
    float4 c0 = cp[0], c1 = cp[1], s0 = sp[0], s1 = sp[1];
    c[0] = c0.x; c[1] = c0.y; c[2] = c0.z; c[3] = c0.w;
    c[4] = c1.x; c[5] = c1.y; c[6] = c1.z; c[7] = c1.w;
    s[0] = s0.x; s[1] = s0.y; s[2] = s0.z; s[3] = s0.w;
    s[4] = s1.x; s[5] = s1.y; s[6] = s1.z; s[7] = s1.w;
  }

#pragma unroll
  for (int pass = 0; pass < 2; pass++) {
    int u;
    if (pass == 0) {
      u = tid >> 4;  // q heads 0..15
    } else {
      if (tid >= 16) break;
      u = 16;  // k
    }
    const bf16x8_t xv = *(const bf16x8_t*)(src + u * 128 + d0);
    const bf16x8_t pv = *(const bf16x8_t*)(src + u * 128 + (d0 ^ 64));
    const unsigned short* xu = (const unsigned short*)&xv;
    const unsigned short* pu = (const unsigned short*)&pv;
    const float qsc = (u < 16) ? 0.011271055f : 1.0f;  // 1/128*log2(e)
    float v[8];
#pragma unroll
    for (int e = 0; e < 8; e++)
      v[e] = (bf2f(xu[e]) * c[e] + sgn * bf2f(pu[e]) * s[e]) * qsc;
    uint4 w;
    w.x = cvtpk(v[0], v[1]);
    w.y = cvtpk(v[2], v[3]);
    w.z = cvtpk(v[4], v[5]);
    w.w = cvtpk(v[6], v[7]);
    unsigned short* dst = (u < 16)
                              ? (qr + ((long)((b * 16 + u) * 2048 + t)) * 128 + d0)
                              : (kr + ((long)(b * 2048 + t)) * 128 + d0);
    *(uint4*)dst = w;
  }
}

// ---------- 5. causal MQA flash attention (v10, unchanged) ----------
__global__ __launch_bounds__(256, 2)
void mqa_attn(const unsigned short* __restrict__ qr,
              const unsigned short* __restrict__ kr,
              const unsigned short* __restrict__ vT,
              unsigned short* __restrict__ ao) {
  __shared__ unsigned short Kb[2][64 * 128];   // 2 x 16KB K tiles
  __shared__ unsigned short Vb[2][128 * 64];   // 2 x 16KB V^T tiles
  __shared__ unsigned short plds[4][16 * 64];  // per-wave P tile (2KB each)
  const int idx = blockIdx.x;  // 512 blocks
  const int pj = idx & 15, h = (idx >> 4) & 15, b = idx >> 8;
  const int tid = threadIdx.x;
  const int wid = tid >> 6, lane = tid & 63;
  const int r = lane & 15, g = lane >> 4;
  const int rs = r & 7;
  char* pw = (char*)&plds[wid][0];

  const unsigned short* kbase = kr + (long)b * 2048 * 128;
  const unsigned short* vbase = vT + (long)b * 128 * 2048;
  const unsigned short* qh = qr + (long)(b * 16 + h) * 2048 * 128;

  const int scol = (tid & 15) ^ ((tid >> 4) & 7);  // K staging src granule
  const int vscol = (tid & 7) ^ ((tid >> 3) & 7);  // V staging src granule

  f32x4_t o[8];
#pragma unroll
  for (int i = 0; i < 8; i++) o[i] = (f32x4_t){0.f, 0.f, 0.f, 0.f};
  float m = 0.f, lsum = 0.f;

  int tile = pj;
  bf16x8_t qf[4];
  {
    const unsigned short* qp = qh + (long)(tile * 64 + wid * 16 + r) * 128 + g * 8;
#pragma unroll
    for (int c = 0; c < 4; c++) qf[c] = *(const bf16x8_t*)(qp + c * 32);
  }

  // prologue: stage K(0) -> Kb[0], V(0) -> Vb[0]
#pragma unroll
  for (int i = 0; i < 4; i++) {
    const int row = i * 16 + (tid >> 4);
    __builtin_amdgcn_global_load_lds(
        (const AS1 void*)(kbase + (long)row * 128 + scol * 8),
        (AS3 void*)(&Kb[0][(i * 256 + tid) * 8]), 16, 0, 0);
  }
#pragma unroll
  for (int i = 0; i < 4; i++) {
    const int vrow = i * 32 + (tid >> 3);
    __builtin_amdgcn_global_load_lds(
        (const AS1 void*)(vbase + (long)vrow * 2048 + vscol * 8),
        (AS3 void*)(&Vb[0][(i * 256 + tid) * 8]), 16, 0, 0);
  }
  asm volatile("s_waitcnt vmcnt(0)" ::: "memory");
  __builtin_amdgcn_s_barrier();

  const int switch_s = pj + 1;
  for (int s = 0; s <= 32; s++) {
    const int cur = s & 1;

    // 0. tile switch: flush tile A (O stores + Q reload) at stage top
    if (s == switch_s) {
      float lt = lsum;
      lt += __shfl_xor(lt, 16);
      lt += __shfl_xor(lt, 32);
      float rl[4];
#pragma unroll
      for (int jj = 0; jj < 4; jj++) rl[jj] = 1.0f / __shfl(lt, 4 * g + jj);
      unsigned short* aop = ao + ((long)(b * 2048 + tile * 64 + wid * 16 + 4 * g)) * 2048 + h * 128 + r;
#pragma unroll
      for (int dt = 0; dt < 8; dt++)
#pragma unroll
        for (int jj = 0; jj < 4; jj++)
          aop[(long)jj * 2048 + dt * 16] = f2bf(o[dt][jj] * rl[jj]);
      tile = 31 - pj;
      const unsigned short* qp = qh + (long)(tile * 64 + wid * 16 + r) * 128 + g * 8;
#pragma unroll
      for (int c = 0; c < 4; c++) qf[c] = *(const bf16x8_t*)(qp + c * 32);
#pragma unroll
      for (int i = 0; i < 8; i++) o[i] = (f32x4_t){0.f, 0.f, 0.f, 0.f};
      m = 0.f;
      lsum = 0.f;
    }

    // 1. staging for NEXT stage: K(s+1) first, then V(s+1)
    if (s < 32) {
      const int kvn = (s + 1 <= pj) ? 64 * (s + 1) : 64 * (s - pj);
#pragma unroll
      for (int i = 0; i < 4; i++) {
        const int row = i * 16 + (tid >> 4);
        __builtin_amdgcn_global_load_lds(
            (const AS1 void*)(kbase + (long)(kvn + row) * 128 + scol * 8),
            (AS3 void*)(&Kb[cur ^ 1][(i * 256 + tid) * 8]), 16, 0, 0);
      }
      __builtin_amdgcn_sched_barrier(0);
#pragma unroll
      for (int i = 0; i < 4; i++) {
        const int vrow = i * 32 + (tid >> 3);
        __builtin_amdgcn_global_load_lds(
            (const AS1 void*)(vbase + (long)vrow * 2048 + kvn + vscol * 8),
            (AS3 void*)(&Vb[cur ^ 1][(i * 256 + tid) * 8]), 16, 0, 0);
      }
    }
    __builtin_amdgcn_sched_barrier(0);

    // 2. QK^T from LDS K tile
    f32x4_t sc[4];
#pragma unroll
    for (int t = 0; t < 4; t++) sc[t] = (f32x4_t){0.f, 0.f, 0.f, 0.f};
    const unsigned short* Kcur = &Kb[cur][0];
    __builtin_amdgcn_s_setprio(1);
#pragma unroll
    for (int t = 0; t < 4; t++) {
      const unsigned short* krow = Kcur + (16 * t + r) * 128;
#pragma unroll
      for (int c = 0; c < 4; c++) {
        const bf16x8_t kf = *(const bf16x8_t*)(krow + (((4 * c + g) ^ rs) << 3));
        sc[t] = __builtin_amdgcn_mfma_f32_16x16x32_bf16(kf, qf[c], sc[t], 0, 0, 0);
      }
    }
    __builtin_amdgcn_s_setprio(0);

    // 3. causal mask on the current tile's last stage
    if (s == pj || s == 32) {
#pragma unroll
      for (int t = 0; t < 4; t++)
#pragma unroll
        for (int jj = 0; jj < 4; jj++)
          if (t * 16 + 4 * g + jj > wid * 16 + r) sc[t][jj] = -1e30f;
    }
    // 4. softmax in exp2 domain (defer-max fast path), fmax TREE
    float mx01 = fmaxf(fmaxf(sc[0][0], sc[0][1]), fmaxf(sc[0][2], sc[0][3]));
    float mx23 = fmaxf(fmaxf(sc[1][0], sc[1][1]), fmaxf(sc[1][2], sc[1][3]));
    float mx45 = fmaxf(fmaxf(sc[2][0], sc[2][1]), fmaxf(sc[2][2], sc[2][3]));
    float mx67 = fmaxf(fmaxf(sc[3][0], sc[3][1]), fmaxf(sc[3][2], sc[3][3]));
    const float lm = fmaxf(fmaxf(mx01, mx23), fmaxf(mx45, mx67));
    if (!__all(lm <= m + 11.5f)) {  // rare rescale path (11.5 bits ~ 8 nats)
      float pm = lm;
      pm = fmaxf(pm, __shfl_xor(pm, 16));
      pm = fmaxf(pm, __shfl_xor(pm, 32));
      const float mnew = fmaxf(m, pm);
      const float alpha = __builtin_amdgcn_exp2f(m - mnew);
      lsum *= alpha;
      float aj[4];
#pragma unroll
      for (int jj = 0; jj < 4; jj++) aj[jj] = __shfl(alpha, 4 * g + jj);
#pragma unroll
      for (int dt = 0; dt < 8; dt++) {
        o[dt][0] *= aj[0]; o[dt][1] *= aj[1]; o[dt][2] *= aj[2]; o[dt][3] *= aj[3];
      }
      m = mnew;
    }
    float p[16];
#pragma unroll
    for (int t = 0; t < 4; t++)
#pragma unroll
      for (int jj = 0; jj < 4; jj++) p[4 * t + jj] = __builtin_amdgcn_exp2f(sc[t][jj] - m);
    float ls = 0.f;
#pragma unroll
    for (int i = 0; i < 16; i++) ls += p[i];
    lsum += ls;

    // 5. P redistribute through per-wave LDS tile (HW cvt_pk packing)
    asm volatile("" ::: "memory");
#pragma unroll
    for (int t = 0; t < 4; t++) {
      uint2 w = {cvtpk(p[4 * t], p[4 * t + 1]), cvtpk(p[4 * t + 2], p[4 * t + 3])};
      *(uint2*)(pw + r * 128 + (((2 * t + (g >> 1)) ^ rs) << 4) + ((g & 1) << 3)) = w;
    }
    asm volatile("s_waitcnt lgkmcnt(0)" ::: "memory");
    const bf16x8_t pa0 = *(const bf16x8_t*)(pw + r * 128 + ((g ^ rs) << 4));
    const bf16x8_t pa1 = *(const bf16x8_t*)(pw + r * 128 + (((4 + g) ^ rs) << 4));

    // 6. V(s) visibility: staged a FULL stage ago; only K/V(s+1) are newer
    if (s < 32)
      asm volatile("s_waitcnt vmcnt(8)" ::: "memory");
    else
      asm volatile("s_waitcnt vmcnt(0)" ::: "memory");
    __builtin_amdgcn_s_barrier();

    // 7. PV from LDS V tile
    const unsigned short* Vcur = &Vb[cur][0];
    __builtin_amdgcn_s_setprio(1);
#pragma unroll
    for (int dt = 0; dt < 8; dt++) {
      const bf16x8_t vfA = *(const bf16x8_t*)(Vcur + (dt * 16 + r) * 64 + ((g ^ rs) << 3));
      o[dt] = __builtin_amdgcn_mfma_f32_16x16x32_bf16(pa0, vfA, o[dt], 0, 0, 0);
    }
#pragma unroll
    for (int dt = 0; dt < 8; dt++) {
      const bf16x8_t vfB = *(const bf16x8_t*)(Vcur + (dt * 16 + r) * 64 + (((4 + g) ^ rs) << 3));
      o[dt] = __builtin_amdgcn_mfma_f32_16x16x32_bf16(pa1, vfB, o[dt], 0, 0, 0);
    }
    __builtin_amdgcn_s_setprio(0);

    // 8. end: K(s+1) landed (V(s+1) may still fly) -> next stage QK safe
    if (s < 32)
      asm volatile("s_waitcnt vmcnt(4)" ::: "memory");
    else
      asm volatile("s_waitcnt vmcnt(0)" ::: "memory");
    __builtin_amdgcn_s_barrier();
  }
  // epilogue: flush tile B
  {
    float lt = lsum;
    lt += __shfl_xor(lt, 16);
    lt += __shfl_xor(lt, 32);
    float rl[4];
#pragma unroll
    for (int jj = 0; jj < 4; jj++) rl[jj] = 1.0f / __shfl(lt, 4 * g + jj);
    unsigned short* aop = ao + ((long)(b * 2048 + tile * 64 + wid * 16 + 4 * g)) * 2048 + h * 128 + r;
#pragma unroll
    for (int dt = 0; dt < 8; dt++)
#pragma unroll
      for (int jj = 0; jj < 4; jj++)
        aop[(long)jj * 2048 + dt * 16] = f2bf(o[dt][jj] * rl[jj]);
  }
}

extern "C" void kernel_launch(void* const* d_in, const int* in_sizes, int n_in,
                              void* d_out, int out_size, void* d_ws, size_t ws_size,
                              hipStream_t stream) {
  const float* x    = (const float*)d_in[0];
  const float* sinp = (const float*)d_in[1];
  const float* cosp = (const float*)d_in[2];
  const float* Wqkv = (const float*)d_in[3];
  const float* Wo   = (const float*)d_in[4];
  float* out = (float*)d_out;
  char* ws = (char*)d_ws;

  const int B = 2, T = 2048, D = 2048, H = 16, HD = 128;
  const int M = B * T;        // 4096
  const int NQ = D + 2 * HD;  // 2304

  unsigned short* xb    = (unsigned short*)(ws + 0);         // 16,777,216
  unsigned short* wqkvT = (unsigned short*)(ws + 16777216);  //  9,437,184
  unsigned short* woT   = (unsigned short*)(ws + 26214400);  //  8,388,608
  unsigned short* qkvh  = (unsigned short*)(ws + 34603008);  // 18,874,368 (bf16)
  unsigned short* qr    = (unsigned short*)(ws + 53477376);  // 16,777,216
  unsigned short* kr    = (unsigned short*)(ws + 70254592);  //  1,048,576
  unsigned short* vT    = (unsigned short*)(ws + 71303168);  //  1,048,576
  unsigned short* ao    = xb;  // reuse xb after GEMM1

  dim3 tb(64, 4);
  cvt_bf16_kernel<<<(M * D) / 1024, 256, 0, stream>>>(x, xb);
  transpose_f32_bf16<<<dim3(NQ / 64, D / 64, 1), tb, 0, stream>>>(Wqkv, wqkvT, NQ, D, 0, 0);
  transpose_f32_bf16<<<dim3(D / 64, D / 64, 1), tb, 0, stream>>>(Wo, woT, D, D, 0, 0);
  // qkvh (bf16) = x @ Wqkv
  gemm_bt_h<<<dim3((NQ / 128) * (M / 128)), 256, 0, stream>>>(xb, wqkvT, qkvh, M, NQ, D, NQ / 128);
  // rope (vectorized bf16 in)
  rope_h<<<M, 256, 0, stream>>>(qkvh, sinp, cosp, qr, kr);
  // vT: qkvh cols 2176..2304 -> (B,128,T), bf16 transpose
  transpose_bf16<<<dim3(HD / 64, T / 64, B), tb, 0, stream>>>(
      qkvh + 2176, vT, NQ, T, (long)T * NQ, (long)HD * T);
  mqa_attn<<<dim3(512), 256, 0, stream>>>(qr, kr, vT, ao);
  gemm_bt<<<dim3((D / 128) * (M / 128)), 256, 0, stream>>>(ao, woT, out, M, D, D, D / 128);
}

// Round 18
// 191.649 us; speedup vs baseline: 1.2120x; 1.0318x over previous
//
#include <hip/hip_runtime.h>
#include <stdint.h>

typedef __bf16 bf16x8_t __attribute__((ext_vector_type(8)));
typedef float f32x4_t __attribute__((ext_vector_type(4)));

#define AS1 __attribute__((address_space(1)))
#define AS3 __attribute__((address_space(3)))

static __device__ __forceinline__ unsigned short f2bf(float f) {
  union { float f; unsigned u; } a;
  a.f = f;
  unsigned r = a.u + 0x7fffu + ((a.u >> 16) & 1u);
  return (unsigned short)(r >> 16);
}

static __device__ __forceinline__ float bf2f(unsigned short u) {
  union { unsigned u; float f; } a;
  a.u = (unsigned)u << 16;
  return a.f;
}

// HW packed f32x2 -> bf16x2 (RNE)
static __device__ __forceinline__ unsigned cvtpk(float lo, float hi) {
  unsigned r;
  asm("v_cvt_pk_bf16_f32 %0, %1, %2" : "=v"(r) : "v"(lo), "v"(hi));
  return r;
}

// ---------- 1. fused prep: x->bf16 (blocks 0..8191), Wqkv^T (1152), Wo^T (1024) ----------
__global__ __launch_bounds__(256) void prep_kernel(
    const float* __restrict__ x, unsigned short* __restrict__ xb,
    const float* __restrict__ Wqkv, unsigned short* __restrict__ wqkvT,
    const float* __restrict__ Wo, unsigned short* __restrict__ woT) {
  __shared__ float tile[64][65];
  const int bid = blockIdx.x;
  const int tid = threadIdx.x;
  if (bid < 8192) {  // cvt: 4096x2048 fp32 -> bf16, 1024 elems/block
    const long i = ((long)bid * 256 + tid) * 4;
    float4 v = *(const float4*)(x + i);
    ushort4 o;
    o.x = f2bf(v.x);
    o.y = f2bf(v.y);
    o.z = f2bf(v.z);
    o.w = f2bf(v.w);
    *(ushort4*)(xb + i) = o;
    return;
  }
  // weight transposes: fp32 [R][C] -> bf16 [C][R]
  const float* src;
  unsigned short* dst;
  int ld, dld, c0, r0;
  if (bid < 8192 + 1152) {  // Wqkv [2048][2304] -> wqkvT [2304][2048]
    const int idx = bid - 8192;
    c0 = (idx % 36) * 64;
    r0 = (idx / 36) * 64;
    src = Wqkv; dst = wqkvT; ld = 2304; dld = 2048;
  } else {  // Wo [2048][2048] -> woT [2048][2048]
    const int idx = bid - 8192 - 1152;
    c0 = (idx & 31) * 64;
    r0 = (idx >> 5) * 64;
    src = Wo; dst = woT; ld = 2048; dld = 2048;
  }
  const int tx = tid & 63, ty = tid >> 6;
#pragma unroll
  for (int j = 0; j < 64; j += 4)
    tile[ty + j][tx] = src[(long)(r0 + ty + j) * ld + (c0 + tx)];
  __syncthreads();
#pragma unroll
  for (int j = 0; j < 64; j += 4)
    dst[(long)(c0 + ty + j) * dld + (r0 + tx)] = f2bf(tile[tx][ty + j]);
}

#define STAGE_G(buf, kt)                                                              \
  {                                                                                   \
    _Pragma("unroll") for (int i = 0; i < 2; i++) {                                   \
      const int chunk = (i * 4 + wid) * 64 + lane;                                    \
      const int row = chunk >> 2;                                                     \
      __builtin_amdgcn_global_load_lds(                                               \
          (const AS1 void*)(A + (bm + row) * K + (kt) + sslot * 8),                   \
          (AS3 void*)(&As[buf][chunk * 8]), 16, 0, 0);                                \
      __builtin_amdgcn_global_load_lds(                                               \
          (const AS1 void*)(Bt + (bn + row) * K + (kt) + sslot * 8),                  \
          (AS3 void*)(&Bs[buf][chunk * 8]), 16, 0, 0);                                \
    }                                                                                 \
  }

// ---------- 3a. GEMM fp32-out (r9 pipeline: 3-buf LDS, counted vmcnt, slot swizzle) ----------
__global__ __launch_bounds__(256) void gemm_bt(const unsigned short* __restrict__ A,
                                               const unsigned short* __restrict__ Bt,
                                               float* __restrict__ C,
                                               int M, int N, int K, int nx) {
  __shared__ unsigned short As[3][128 * 32];
  __shared__ unsigned short Bs[3][128 * 32];
  const int nwg = gridDim.x;
  const int bid = blockIdx.x;
  const int swz = (bid & 7) * (nwg >> 3) + (bid >> 3);
  const int by = swz / nx;
  const int bx = swz - by * nx;

  const int tid = threadIdx.x;
  const int wid = tid >> 6, lane = tid & 63;
  const int r16 = lane & 15, g = lane >> 4;
  const long bm = (long)by * 128;
  const long bn = (long)bx * 128;
  const int wr = (wid >> 1) * 64, wc = (wid & 1) * 64;
  const int gr = g ^ (r16 & 3);
  const int sslot = (lane & 3) ^ ((lane >> 2) & 3);

  f32x4_t acc[4][4];
#pragma unroll
  for (int i = 0; i < 4; i++)
#pragma unroll
    for (int j = 0; j < 4; j++) acc[i][j] = (f32x4_t){0.f, 0.f, 0.f, 0.f};

  const int NT = K >> 5;

  STAGE_G(0, 0)
  STAGE_G(1, 32)
  asm volatile("s_waitcnt vmcnt(4)" ::: "memory");
  __builtin_amdgcn_s_barrier();

  for (int T = 0; T < NT; T++) {
    const int cur = T % 3;
    if (T + 2 < NT) {
      const int nb = (T + 2) % 3;
      STAGE_G(nb, (T + 2) * 32)
    }
    __builtin_amdgcn_sched_barrier(0);
    bf16x8_t af[4], bfr[4];
#pragma unroll
    for (int mi = 0; mi < 4; mi++)
      af[mi] = *(const bf16x8_t*)(&As[cur][(wr + mi * 16 + r16) * 32 + gr * 8]);
#pragma unroll
    for (int ni = 0; ni < 4; ni++)
      bfr[ni] = *(const bf16x8_t*)(&Bs[cur][(wc + ni * 16 + r16) * 32 + gr * 8]);
    __builtin_amdgcn_s_setprio(1);
#pragma unroll
    for (int mi = 0; mi < 4; mi++)
#pragma unroll
      for (int ni = 0; ni < 4; ni++)
        acc[mi][ni] = __builtin_amdgcn_mfma_f32_16x16x32_bf16(af[mi], bfr[ni], acc[mi][ni], 0, 0, 0);
    __builtin_amdgcn_s_setprio(0);
    if (T + 2 < NT)
      asm volatile("s_waitcnt vmcnt(4)" ::: "memory");
    else
      asm volatile("s_waitcnt vmcnt(0)" ::: "memory");
    __builtin_amdgcn_s_barrier();
  }

#pragma unroll
  for (int mi = 0; mi < 4; mi++)
#pragma unroll
    for (int ni = 0; ni < 4; ni++) {
      const long rowb = bm + wr + mi * 16 + 4 * g;
      const long colb = bn + wc + ni * 16 + r16;
#pragma unroll
      for (int j = 0; j < 4; j++)
        C[(rowb + j) * N + colb] = acc[mi][ni][j];
    }
}

// ---------- 3b. GEMM bf16-out (identical pipeline; halves C write traffic) ----------
__global__ __launch_bounds__(256) void gemm_bt_h(const unsigned short* __restrict__ A,
                                                 const unsigned short* __restrict__ Bt,
                                                 unsigned short* __restrict__ C,
                                                 int M, int N, int K, int nx) {
  __shared__ unsigned short As[3][128 * 32];
  __shared__ unsigned short Bs[3][128 * 32];
  const int nwg = gridDim.x;
  const int bid = blockIdx.x;
  const int swz = (bid & 7) * (nwg >> 3) + (bid >> 3);
  const int by = swz / nx;
  const int bx = swz - by * nx;

  const int tid = threadIdx.x;
  const int wid = tid >> 6, lane = tid & 63;
  const int r16 = lane & 15, g = lane >> 4;
  const long bm = (long)by * 128;
  const long bn = (long)bx * 128;
  const int wr = (wid >> 1) * 64, wc = (wid & 1) * 64;
  const int gr = g ^ (r16 & 3);
  const int sslot = (lane & 3) ^ ((lane >> 2) & 3);

  f32x4_t acc[4][4];
#pragma unroll
  for (int i = 0; i < 4; i++)
#pragma unroll
    for (int j = 0; j < 4; j++) acc[i][j] = (f32x4_t){0.f, 0.f, 0.f, 0.f};

  const int NT = K >> 5;

  STAGE_G(0, 0)
  STAGE_G(1, 32)
  asm volatile("s_waitcnt vmcnt(4)" ::: "memory");
  __builtin_amdgcn_s_barrier();

  for (int T = 0; T < NT; T++) {
    const int cur = T % 3;
    if (T + 2 < NT) {
      const int nb = (T + 2) % 3;
      STAGE_G(nb, (T + 2) * 32)
    }
    __builtin_amdgcn_sched_barrier(0);
    bf16x8_t af[4], bfr[4];
#pragma unroll
    for (int mi = 0; mi < 4; mi++)
      af[mi] = *(const bf16x8_t*)(&As[cur][(wr + mi * 16 + r16) * 32 + gr * 8]);
#pragma unroll
    for (int ni = 0; ni < 4; ni++)
      bfr[ni] = *(const bf16x8_t*)(&Bs[cur][(wc + ni * 16 + r16) * 32 + gr * 8]);
    __builtin_amdgcn_s_setprio(1);
#pragma unroll
    for (int mi = 0; mi < 4; mi++)
#pragma unroll
      for (int ni = 0; ni < 4; ni++)
        acc[mi][ni] = __builtin_amdgcn_mfma_f32_16x16x32_bf16(af[mi], bfr[ni], acc[mi][ni], 0, 0, 0);
    __builtin_amdgcn_s_setprio(0);
    if (T + 2 < NT)
      asm volatile("s_waitcnt vmcnt(4)" ::: "memory");
    else
      asm volatile("s_waitcnt vmcnt(0)" ::: "memory");
    __builtin_amdgcn_s_barrier();
  }

#pragma unroll
  for (int mi = 0; mi < 4; mi++)
#pragma unroll
    for (int ni = 0; ni < 4; ni++) {
      const long rowb = bm + wr + mi * 16 + 4 * g;
      const long colb = bn + wc + ni * 16 + r16;
#pragma unroll
      for (int j = 0; j < 4; j++)
        C[(rowb + j) * N + colb] = f2bf(acc[mi][ni][j]);
    }
}
#undef STAGE_G

// ---------- 4. fused rope (blocks 0..4095) + vT transpose (128 tiles) ----------
__global__ __launch_bounds__(256) void rope_vt_kernel(
    const unsigned short* __restrict__ qkvh,
    const float* __restrict__ sinp, const float* __restrict__ cosp,
    unsigned short* __restrict__ qr, unsigned short* __restrict__ kr,
    unsigned short* __restrict__ vT) {
  __shared__ unsigned short tileb[64][66];
  const int bid = blockIdx.x;
  const int tid = threadIdx.x;
  if (bid < 4096) {  // rope: row = b*2048 + t
    const int b = bid >> 11, t = bid & 2047;
    const unsigned short* src = qkvh + (long)bid * 2304;
    const int d0 = (tid & 15) * 8;
    const float sgn = (d0 < 64) ? -1.f : 1.f;
    float c[8], s[8];
    {
      const float4* cp = (const float4*)(cosp + t * 128 + d0);
      const float4* sp = (const float4*)(sinp + t * 128 + d0);
      float4 c0 = cp[0], c1 = cp[1], s0 = sp[0], s1 = sp[1];
      c[0] = c0.x; c[1] = c0.y; c[2] = c0.z; c[3] = c0.w;
      c[4] = c1.x; c[5] = c1.y; c[6] = c1.z; c[7] = c1.w;
      s[0] = s0.x; s[1] = s0.y; s[2] = s0.z; s[3] = s0.w;
      s[4] = s1.x; s[5] = s1.y; s[6] = s1.z; s[7] = s1.w;
    }
#pragma unroll
    for (int pass = 0; pass < 2; pass++) {
      int u;
      if (pass == 0) {
        u = tid >> 4;  // q heads 0..15
      } else {
        if (tid >= 16) break;
        u = 16;  // k
      }
      const bf16x8_t xv = *(const bf16x8_t*)(src + u * 128 + d0);
      const bf16x8_t pv = *(const bf16x8_t*)(src + u * 128 + (d0 ^ 64));
      const unsigned short* xu = (const unsigned short*)&xv;
      const unsigned short* pu = (const unsigned short*)&pv;
      const float qsc = (u < 16) ? 0.011271055f : 1.0f;  // 1/128*log2(e)
      float v[8];
#pragma unroll
      for (int e = 0; e < 8; e++)
        v[e] = (bf2f(xu[e]) * c[e] + sgn * bf2f(pu[e]) * s[e]) * qsc;
      uint4 w;
      w.x = cvtpk(v[0], v[1]);
      w.y = cvtpk(v[2], v[3]);
      w.z = cvtpk(v[4], v[5]);
      w.w = cvtpk(v[6], v[7]);
      unsigned short* dst = (u < 16)
                                ? (qr + ((long)((b * 16 + u) * 2048 + t)) * 128 + d0)
                                : (kr + ((long)(b * 2048 + t)) * 128 + d0);
      *(uint4*)dst = w;
    }
    return;
  }
  // vT transpose: qkvh cols 2176..2303 -> vT (B,128,T); 64 tiles per batch
  const int idx = bid - 4096;
  const int zb = idx >> 6;
  const int rem = idx & 63;
  const int c0 = (rem & 1) * 64;   // within HD=128
  const int r0 = (rem >> 1) * 64;  // within T=2048
  const unsigned short* src = qkvh + 2176 + (long)zb * 2048 * 2304;
  unsigned short* dst = vT + (long)zb * 128 * 2048;
  const int tx = tid & 63, ty = tid >> 6;
#pragma unroll
  for (int j = 0; j < 64; j += 4)
    tileb[ty + j][tx] = src[(long)(r0 + ty + j) * 2304 + (c0 + tx)];
  __syncthreads();
#pragma unroll
  for (int j = 0; j < 64; j += 4)
    dst[(long)(c0 + ty + j) * 2048 + (r0 + tx)] = tileb[tx][ty + j];
}

// ---------- 5. causal MQA flash attention (v10, unchanged) ----------
__global__ __launch_bounds__(256, 2)
void mqa_attn(const unsigned short* __restrict__ qr,
              const unsigned short* __restrict__ kr,
              const unsigned short* __restrict__ vT,
              unsigned short* __restrict__ ao) {
  __shared__ unsigned short Kb[2][64 * 128];   // 2 x 16KB K tiles
  __shared__ unsigned short Vb[2][128 * 64];   // 2 x 16KB V^T tiles
  __shared__ unsigned short plds[4][16 * 64];  // per-wave P tile (2KB each)
  const int idx = blockIdx.x;  // 512 blocks
  const int pj = idx & 15, h = (idx >> 4) & 15, b = idx >> 8;
  const int tid = threadIdx.x;
  const int wid = tid >> 6, lane = tid & 63;
  const int r = lane & 15, g = lane >> 4;
  const int rs = r & 7;
  char* pw = (char*)&plds[wid][0];

  const unsigned short* kbase = kr + (long)b * 2048 * 128;
  const unsigned short* vbase = vT + (long)b * 128 * 2048;
  const unsigned short* qh = qr + (long)(b * 16 + h) * 2048 * 128;

  const int scol = (tid & 15) ^ ((tid >> 4) & 7);  // K staging src granule
  const int vscol = (tid & 7) ^ ((tid >> 3) & 7);  // V staging src granule

  f32x4_t o[8];
#pragma unroll
  for (int i = 0; i < 8; i++) o[i] = (f32x4_t){0.f, 0.f, 0.f, 0.f};
  float m = 0.f, lsum = 0.f;

  int tile = pj;
  bf16x8_t qf[4];
  {
    const unsigned short* qp = qh + (long)(tile * 64 + wid * 16 + r) * 128 + g * 8;
#pragma unroll
    for (int c = 0; c < 4; c++) qf[c] = *(const bf16x8_t*)(qp + c * 32);
  }

  // prologue: stage K(0) -> Kb[0], V(0) -> Vb[0]
#pragma unroll
  for (int i = 0; i < 4; i++) {
    const int row = i * 16 + (tid >> 4);
    __builtin_amdgcn_global_load_lds(
        (const AS1 void*)(kbase + (long)row * 128 + scol * 8),
        (AS3 void*)(&Kb[0][(i * 256 + tid) * 8]), 16, 0, 0);
  }
#pragma unroll
  for (int i = 0; i < 4; i++) {
    const int vrow = i * 32 + (tid >> 3);
    __builtin_amdgcn_global_load_lds(
        (const AS1 void*)(vbase + (long)vrow * 2048 + vscol * 8),
        (AS3 void*)(&Vb[0][(i * 256 + tid) * 8]), 16, 0, 0);
  }
  asm volatile("s_waitcnt vmcnt(0)" ::: "memory");
  __builtin_amdgcn_s_barrier();

  const int switch_s = pj + 1;
  for (int s = 0; s <= 32; s++) {
    const int cur = s & 1;

    // 0. tile switch: flush tile A (O stores + Q reload) at stage top
    if (s == switch_s) {
      float lt = lsum;
      lt += __shfl_xor(lt, 16);
      lt += __shfl_xor(lt, 32);
      float rl[4];
#pragma unroll
      for (int jj = 0; jj < 4; jj++) rl[jj] = 1.0f / __shfl(lt, 4 * g + jj);
      unsigned short* aop = ao + ((long)(b * 2048 + tile * 64 + wid * 16 + 4 * g)) * 2048 + h * 128 + r;
#pragma unroll
      for (int dt = 0; dt < 8; dt++)
#pragma unroll
        for (int jj = 0; jj < 4; jj++)
          aop[(long)jj * 2048 + dt * 16] = f2bf(o[dt][jj] * rl[jj]);
      tile = 31 - pj;
      const unsigned short* qp = qh + (long)(tile * 64 + wid * 16 + r) * 128 + g * 8;
#pragma unroll
      for (int c = 0; c < 4; c++) qf[c] = *(const bf16x8_t*)(qp + c * 32);
#pragma unroll
      for (int i = 0; i < 8; i++) o[i] = (f32x4_t){0.f, 0.f, 0.f, 0.f};
      m = 0.f;
      lsum = 0.f;
    }

    // 1. staging for NEXT stage: K(s+1) first, then V(s+1)
    if (s < 32) {
      const int kvn = (s + 1 <= pj) ? 64 * (s + 1) : 64 * (s - pj);
#pragma unroll
      for (int i = 0; i < 4; i++) {
        const int row = i * 16 + (tid >> 4);
        __builtin_amdgcn_global_load_lds(
            (const AS1 void*)(kbase + (long)(kvn + row) * 128 + scol * 8),
            (AS3 void*)(&Kb[cur ^ 1][(i * 256 + tid) * 8]), 16, 0, 0);
      }
      __builtin_amdgcn_sched_barrier(0);
#pragma unroll
      for (int i = 0; i < 4; i++) {
        const int vrow = i * 32 + (tid >> 3);
        __builtin_amdgcn_global_load_lds(
            (const AS1 void*)(vbase + (long)vrow * 2048 + kvn + vscol * 8),
            (AS3 void*)(&Vb[cur ^ 1][(i * 256 + tid) * 8]), 16, 0, 0);
      }
    }
    __builtin_amdgcn_sched_barrier(0);

    // 2. QK^T from LDS K tile
    f32x4_t sc[4];
#pragma unroll
    for (int t = 0; t < 4; t++) sc[t] = (f32x4_t){0.f, 0.f, 0.f, 0.f};
    const unsigned short* Kcur = &Kb[cur][0];
    __builtin_amdgcn_s_setprio(1);
#pragma unroll
    for (int t = 0; t < 4; t++) {
      const unsigned short* krow = Kcur + (16 * t + r) * 128;
#pragma unroll
      for (int c = 0; c < 4; c++) {
        const bf16x8_t kf = *(const bf16x8_t*)(krow + (((4 * c + g) ^ rs) << 3));
        sc[t] = __builtin_amdgcn_mfma_f32_16x16x32_bf16(kf, qf[c], sc[t], 0, 0, 0);
      }
    }
    __builtin_amdgcn_s_setprio(0);

    // 3. causal mask on the current tile's last stage
    if (s == pj || s == 32) {
#pragma unroll
      for (int t = 0; t < 4; t++)
#pragma unroll
        for (int jj = 0; jj < 4; jj++)
          if (t * 16 + 4 * g + jj > wid * 16 + r) sc[t][jj] = -1e30f;
    }
    // 4. softmax in exp2 domain (defer-max fast path), fmax TREE
    float mx01 = fmaxf(fmaxf(sc[0][0], sc[0][1]), fmaxf(sc[0][2], sc[0][3]));
    float mx23 = fmaxf(fmaxf(sc[1][0], sc[1][1]), fmaxf(sc[1][2], sc[1][3]));
    float mx45 = fmaxf(fmaxf(sc[2][0], sc[2][1]), fmaxf(sc[2][2], sc[2][3]));
    float mx67 = fmaxf(fmaxf(sc[3][0], sc[3][1]), fmaxf(sc[3][2], sc[3][3]));
    const float lm = fmaxf(fmaxf(mx01, mx23), fmaxf(mx45, mx67));
    if (!__all(lm <= m + 11.5f)) {  // rare rescale path (11.5 bits ~ 8 nats)
      float pm = lm;
      pm = fmaxf(pm, __shfl_xor(pm, 16));
      pm = fmaxf(pm, __shfl_xor(pm, 32));
      const float mnew = fmaxf(m, pm);
      const float alpha = __builtin_amdgcn_exp2f(m - mnew);
      lsum *= alpha;
      float aj[4];
#pragma unroll
      for (int jj = 0; jj < 4; jj++) aj[jj] = __shfl(alpha, 4 * g + jj);
#pragma unroll
      for (int dt = 0; dt < 8; dt++) {
        o[dt][0] *= aj[0]; o[dt][1] *= aj[1]; o[dt][2] *= aj[2]; o[dt][3] *= aj[3];
      }
      m = mnew;
    }
    float p[16];
#pragma unroll
    for (int t = 0; t < 4; t++)
#pragma unroll
      for (int jj = 0; jj < 4; jj++) p[4 * t + jj] = __builtin_amdgcn_exp2f(sc[t][jj] - m);
    float ls = 0.f;
#pragma unroll
    for (int i = 0; i < 16; i++) ls += p[i];
    lsum += ls;

    // 5. P redistribute through per-wave LDS tile (HW cvt_pk packing)
    asm volatile("" ::: "memory");
#pragma unroll
    for (int t = 0; t < 4; t++) {
      uint2 w = {cvtpk(p[4 * t], p[4 * t + 1]), cvtpk(p[4 * t + 2], p[4 * t + 3])};
      *(uint2*)(pw + r * 128 + (((2 * t + (g >> 1)) ^ rs) << 4) + ((g & 1) << 3)) = w;
    }
    asm volatile("s_waitcnt lgkmcnt(0)" ::: "memory");
    const bf16x8_t pa0 = *(const bf16x8_t*)(pw + r * 128 + ((g ^ rs) << 4));
    const bf16x8_t pa1 = *(const bf16x8_t*)(pw + r * 128 + (((4 + g) ^ rs) << 4));

    // 6. V(s) visibility: staged a FULL stage ago; only K/V(s+1) are newer
    if (s < 32)
      asm volatile("s_waitcnt vmcnt(8)" ::: "memory");
    else
      asm volatile("s_waitcnt vmcnt(0)" ::: "memory");
    __builtin_amdgcn_s_barrier();

    // 7. PV from LDS V tile
    const unsigned short* Vcur = &Vb[cur][0];
    __builtin_amdgcn_s_setprio(1);
#pragma unroll
    for (int dt = 0; dt < 8; dt++) {
      const bf16x8_t vfA = *(const bf16x8_t*)(Vcur + (dt * 16 + r) * 64 + ((g ^ rs) << 3));
      o[dt] = __builtin_amdgcn_mfma_f32_16x16x32_bf16(pa0, vfA, o[dt], 0, 0, 0);
    }
#pragma unroll
    for (int dt = 0; dt < 8; dt++) {
      const bf16x8_t vfB = *(const bf16x8_t*)(Vcur + (dt * 16 + r) * 64 + (((4 + g) ^ rs) << 3));
      o[dt] = __builtin_amdgcn_mfma_f32_16x16x32_bf16(pa1, vfB, o[dt], 0, 0, 0);
    }
    __builtin_amdgcn_s_setprio(0);

    // 8. end: K(s+1) landed (V(s+1) may still fly) -> next stage QK safe
    if (s < 32)
      asm volatile("s_waitcnt vmcnt(4)" ::: "memory");
    else
      asm volatile("s_waitcnt vmcnt(0)" ::: "memory");
    __builtin_amdgcn_s_barrier();
  }
  // epilogue: flush tile B
  {
    float lt = lsum;
    lt += __shfl_xor(lt, 16);
    lt += __shfl_xor(lt, 32);
    float rl[4];
#pragma unroll
    for (int jj = 0; jj < 4; jj++) rl[jj] = 1.0f / __shfl(lt, 4 * g + jj);
    unsigned short* aop = ao + ((long)(b * 2048 + tile * 64 + wid * 16 + 4 * g)) * 2048 + h * 128 + r;
#pragma unroll
    for (int dt = 0; dt < 8; dt++)
#pragma unroll
      for (int jj = 0; jj < 4; jj++)
        aop[(long)jj * 2048 + dt * 16] = f2bf(o[dt][jj] * rl[jj]);
  }
}

extern "C" void kernel_launch(void* const* d_in, const int* in_sizes, int n_in,
                              void* d_out, int out_size, void* d_ws, size_t ws_size,
                              hipStream_t stream) {
  const float* x    = (const float*)d_in[0];
  const float* sinp = (const float*)d_in[1];
  const float* cosp = (const float*)d_in[2];
  const float* Wqkv = (const float*)d_in[3];
  const float* Wo   = (const float*)d_in[4];
  float* out = (float*)d_out;
  char* ws = (char*)d_ws;

  const int B = 2, T = 2048, D = 2048, H = 16, HD = 128;
  const int M = B * T;        // 4096
  const int NQ = D + 2 * HD;  // 2304

  unsigned short* xb    = (unsigned short*)(ws + 0);         // 16,777,216
  unsigned short* wqkvT = (unsigned short*)(ws + 16777216);  //  9,437,184
  unsigned short* woT   = (unsigned short*)(ws + 26214400);  //  8,388,608
  unsigned short* qkvh  = (unsigned short*)(ws + 34603008);  // 18,874,368 (bf16)
  unsigned short* qr    = (unsigned short*)(ws + 53477376);  // 16,777,216
  unsigned short* kr    = (unsigned short*)(ws + 70254592);  //  1,048,576
  unsigned short* vT    = (unsigned short*)(ws + 71303168);  //  1,048,576
  unsigned short* ao    = xb;  // reuse xb after GEMM1

  // fused prep: cvt (8192) + WqkvT (1152) + WoT (1024)
  prep_kernel<<<dim3(8192 + 1152 + 1024), 256, 0, stream>>>(x, xb, Wqkv, wqkvT, Wo, woT);
  // qkvh (bf16) = x @ Wqkv
  gemm_bt_h<<<dim3((NQ / 128) * (M / 128)), 256, 0, stream>>>(xb, wqkvT, qkvh, M, NQ, D, NQ / 128);
  // fused rope (4096) + vT transpose (128)
  rope_vt_kernel<<<dim3(4096 + 128), 256, 0, stream>>>(qkvh, sinp, cosp, qr, kr, vT);
  mqa_attn<<<dim3(512), 256, 0, stream>>>(qr, kr, vT, ao);
  gemm_bt<<<dim3((D / 128) * (M / 128)), 256, 0, stream>>>(ao, woT, out, M, D, D, D / 128);
}